// Round 4
// baseline (801.209 us; speedup 1.0000x reference)
//
#include <hip/hip_runtime.h>
#include <stdint.h>

// Problem constants
#define B_ 4
#define S_ 2048
#define D_ 1024
#define H_ 16
#define DK_ 64
#define M_ (B_*S_)   // 8192 rows

typedef __attribute__((ext_vector_type(8))) short bhalf8;   // 8 x bf16 (4 VGPRs)
typedef __attribute__((ext_vector_type(4))) short bhalf4;   // 4 x bf16 (2 VGPRs)
typedef __attribute__((ext_vector_type(4))) float floatx4;  // MFMA accumulator
typedef unsigned short bfu;
typedef unsigned int u32;

// fp32 -> bf16 (RNE), branchless
__device__ __forceinline__ bfu f2bf(float f) {
  union { float f; u32 u; } v; v.f = f;
  u32 r = v.u + 0x7FFFu + ((v.u >> 16) & 1u);
  return (bfu)(r >> 16);
}

// pack two fp32 -> one u32 of 2 bf16 (RNE), via v_perm byte select
__device__ __forceinline__ u32 packbf(float a, float b) {
  union { float f; u32 u; } x, y; x.f = a; y.f = b;
  u32 ra = x.u + 0x7FFFu + ((x.u >> 16) & 1u);
  u32 rb = y.u + 0x7FFFu + ((y.u >> 16) & 1u);
  // result = ra[31:16] | rb[31:16]<<16 : S1=ra (bytes 0-3), S0=rb (bytes 4-7)
  return __builtin_amdgcn_perm(rb, ra, 0x07060302u);
}

// ---------------- conversion kernel ----------------
__global__ void cvt_f32_bf16(const float* __restrict__ src, bfu* __restrict__ dst, int n) {
  int i = (blockIdx.x * blockDim.x + threadIdx.x) * 4;
  if (i >= n) return;
  float4 v = *(const float4*)(src + i);
  ushort4 o;
  o.x = f2bf(v.x); o.y = f2bf(v.y); o.z = f2bf(v.z); o.w = f2bf(v.w);
  *(ushort4*)(dst + i) = o;
}

// ---------------- GEMM core: C[128x128] = A[M,K] * B[N,K]^T (both K-contig bf16) ----------------
__device__ __forceinline__ void gemm_core(const bfu* __restrict__ A,
                                          const bfu* __restrict__ Bw,
                                          bfu* aT, bfu* bT,
                                          int m0, int n0,
                                          floatx4 (&acc)[4][4])
{
  const int tid  = threadIdx.x;
  const int lane = tid & 63;
  const int g    = lane >> 4;
  const int i16  = lane & 15;
  const int w    = tid >> 6;
  const int wm   = w >> 1, wn = w & 1;

  for (int k0 = 0; k0 < D_; k0 += 64) {
    bhalf8 ra[4], rb[4];
#pragma unroll
    for (int l = 0; l < 4; ++l) {
      int e = (l * 256 + tid) * 8;
      int row = e >> 6, col = e & 63;
      ra[l] = *(const bhalf8*)(A  + (size_t)(m0 + row) * D_ + k0 + col);
      rb[l] = *(const bhalf8*)(Bw + (size_t)(n0 + row) * D_ + k0 + col);
    }
    __syncthreads();
#pragma unroll
    for (int l = 0; l < 4; ++l) {
      int e = (l * 256 + tid) * 8;
      int row = e >> 6, colb = (e & 63) * 2;
      int sw = colb ^ ((row & 7) << 4);
      *(bhalf8*)((char*)aT + row * 128 + sw) = ra[l];
      *(bhalf8*)((char*)bT + row * 128 + sw) = rb[l];
    }
    __syncthreads();
#pragma unroll
    for (int kb = 0; kb < 2; ++kb) {
      bhalf8 af[4], bf[4];
#pragma unroll
      for (int f = 0; f < 4; ++f) {
        int arow = wm * 64 + f * 16 + i16;
        af[f] = *(const bhalf8*)((const char*)aT + arow * 128 + ((kb * 64 + g * 16) ^ ((arow & 7) << 4)));
        int brow = wn * 64 + f * 16 + i16;
        bf[f] = *(const bhalf8*)((const char*)bT + brow * 128 + ((kb * 64 + g * 16) ^ ((brow & 7) << 4)));
      }
#pragma unroll
      for (int fm = 0; fm < 4; ++fm)
#pragma unroll
        for (int fn = 0; fn < 4; ++fn)
          acc[fm][fn] = __builtin_amdgcn_mfma_f32_16x16x32_bf16(af[fm], bf[fn], acc[fm][fn], 0, 0, 0);
    }
  }
}

// ---------------- QKV projection GEMM ----------------
__global__ __launch_bounds__(256) void proj_gemm(const bfu* __restrict__ xb,
                                                 const bfu* __restrict__ wqb,
                                                 const bfu* __restrict__ wkb,
                                                 const bfu* __restrict__ wvb,
                                                 bfu* __restrict__ Qd,
                                                 bfu* __restrict__ Kd,
                                                 bfu* __restrict__ Vtd)
{
  __shared__ bfu aT[128 * 64], bT[128 * 64];
  const int z = blockIdx.z;
  const bfu* Bw = (z == 0) ? wqb : (z == 1) ? wkb : wvb;
  bfu* dst      = (z == 0) ? Qd  : (z == 1) ? Kd  : Vtd;

  floatx4 acc[4][4] = {};
  const int m0 = blockIdx.y * 128, n0 = blockIdx.x * 128;
  gemm_core(xb, Bw, aT, bT, m0, n0, acc);

  const int lane = threadIdx.x & 63;
  const int g = lane >> 4, i16 = lane & 15;
  const int w = threadIdx.x >> 6, wm = w >> 1, wn = w & 1;
#pragma unroll
  for (int fm = 0; fm < 4; ++fm) {
#pragma unroll
    for (int fn = 0; fn < 4; ++fn) {
      int col = n0 + wn * 64 + fn * 16 + i16;
      int h = col >> 6, dk = col & 63;
#pragma unroll
      for (int r = 0; r < 4; ++r) {
        int mrow = m0 + wm * 64 + fm * 16 + g * 4 + r;
        int b = mrow >> 11, s = mrow & (S_ - 1);
        size_t idx = (z == 2)
            ? ((size_t)((b * H_ + h) * DK_ + dk)) * S_ + s    // V^T
            : ((size_t)((b * H_ + h) * S_ + s)) * DK_ + dk;   // Q,K
        dst[idx] = f2bf(acc[fm][fn][r]);
      }
    }
  }
}

// ---------------- flash attention (causal), swapped-operand, LDS-free ----------------
// grid (S/64, B*H), 256 thr = 4 independent waves; wave w owns q rows [q0+16w, +16)
// S^T = mfma(K, Q): lane holds S[kv=16cb+4g+r][q=i16] -> per-lane q, in-register softmax.
// PV swapped: O^T = V^T @ P^T via mfma_16x16x16bf16_1k (K=16 frag = 4 contig kv = C layout).
__global__ __launch_bounds__(256) void attn_kernel(const bfu* __restrict__ Q,
                                                   const bfu* __restrict__ Kc,
                                                   const bfu* __restrict__ Vt,
                                                   bfu* __restrict__ Oc)
{
  const int tid = threadIdx.x;
  const int lane = tid & 63;
  const int w = tid >> 6;
  const int g = lane >> 4, i16 = lane & 15;
  const int bh = blockIdx.y;
  const int q0 = blockIdx.x * 64;
  const int qr = q0 + w * 16;

  const bfu* Qb = Q  + (size_t)bh * S_ * DK_;
  const bfu* Kb = Kc + (size_t)bh * S_ * DK_;
  const bfu* Vb = Vt + (size_t)bh * DK_ * S_;

  const float C2 = 0.125f * 1.44269504f;   // dk^-0.5 * log2(e) folded

  // Q B-frags hoisted (col=q=i16, k=dk)
  bhalf8 qa[2];
#pragma unroll
  for (int kb = 0; kb < 2; ++kb)
    qa[kb] = *(const bhalf8*)(Qb + (size_t)(qr + i16) * DK_ + kb * 32 + g * 8);

  floatx4 ot[4] = {};          // O^T: col=q=i16, row=dk= da*16 + g*4+r
  float mraw = -3.0e38f;
  float mC2  = -3.0e38f * C2;
  float lp   = 0.f;            // partial l (this lane's 16 kv slots)

  const int ntiles = blockIdx.x + 1;
  for (int t = 0; t < ntiles; ++t) {
    const int kv0 = t * 64;
    // ---- S^T = K @ Q^T ----
    floatx4 sa[4] = {};
#pragma unroll
    for (int cb = 0; cb < 4; ++cb) {
#pragma unroll
      for (int kb = 0; kb < 2; ++kb) {
        bhalf8 kf = *(const bhalf8*)(Kb + (size_t)(kv0 + cb * 16 + i16) * DK_ + kb * 32 + g * 8);
        sa[cb] = __builtin_amdgcn_mfma_f32_16x16x32_bf16(kf, qa[kb], sa[cb], 0, 0, 0);
      }
    }
    // ---- causal mask (wave-uniform: only last tile is partial) ----
    if (t == ntiles - 1) {
#pragma unroll
      for (int cb = 0; cb < 4; ++cb)
#pragma unroll
        for (int r = 0; r < 4; ++r)
          if (kv0 + cb * 16 + g * 4 + r > qr + i16) sa[cb][r] = -3.0e38f;
    }
    // ---- row max (per-lane 16 + 2 shfl across g groups) ----
    float pm = -3.0e38f;
#pragma unroll
    for (int cb = 0; cb < 4; ++cb)
#pragma unroll
      for (int r = 0; r < 4; ++r)
        pm = fmaxf(pm, sa[cb][r]);
    pm = fmaxf(pm, __shfl_xor(pm, 16));
    pm = fmaxf(pm, __shfl_xor(pm, 32));
    const float mn = fmaxf(mraw, pm);
    const float mnC2 = mn * C2;
    const float al = exp2f(mC2 - mnC2);
    mraw = mn; mC2 = mnC2;
    const float nm = -mnC2;
    // ---- P = exp2(S*C2 - mn*C2); pack to bf16 pairs ----
    u32 pk[8];
    float ps = 0.f;
#pragma unroll
    for (int cb = 0; cb < 4; ++cb) {
      float p0 = exp2f(__builtin_fmaf(sa[cb][0], C2, nm));
      float p1 = exp2f(__builtin_fmaf(sa[cb][1], C2, nm));
      float p2 = exp2f(__builtin_fmaf(sa[cb][2], C2, nm));
      float p3 = exp2f(__builtin_fmaf(sa[cb][3], C2, nm));
      ps += (p0 + p1) + (p2 + p3);
      pk[cb * 2]     = packbf(p0, p1);
      pk[cb * 2 + 1] = packbf(p2, p3);
    }
    lp = lp * al + ps;
    // ---- rescale O^T ----
#pragma unroll
    for (int da = 0; da < 4; ++da)
#pragma unroll
      for (int r = 0; r < 4; ++r)
        ot[da][r] *= al;
    // ---- O^T += V^T @ P^T  (16x16x16, K=16: frag = 4 contiguous kv) ----
#pragma unroll
    for (int da = 0; da < 4; ++da) {
#pragma unroll
      for (int cb = 0; cb < 4; ++cb) {
        bhalf4 vf = *(const bhalf4*)(Vb + (size_t)(da * 16 + i16) * S_ + kv0 + cb * 16 + g * 4);
        union { u32 u[2]; bhalf4 h; } pu;
        pu.u[0] = pk[cb * 2]; pu.u[1] = pk[cb * 2 + 1];
        ot[da] = __builtin_amdgcn_mfma_f32_16x16x16bf16_1k(vf, pu.h, ot[da], 0, 0, 0);
      }
    }
  }
  // ---- epilogue: reduce l across g groups, divide, store O^T packed ----
  lp += __shfl_xor(lp, 16);
  lp += __shfl_xor(lp, 32);
  const float rl = 1.0f / lp;
  const int b = bh >> 4, h = bh & 15;
  const size_t rowbase = (size_t)(b * S_ + qr + i16) * D_ + h * 64;
#pragma unroll
  for (int da = 0; da < 4; ++da) {
    ushort4 ov;
    ov.x = f2bf(ot[da][0] * rl);
    ov.y = f2bf(ot[da][1] * rl);
    ov.z = f2bf(ot[da][2] * rl);
    ov.w = f2bf(ot[da][3] * rl);
    *(ushort4*)(Oc + rowbase + da * 16 + g * 4) = ov;
  }
}

// ---------------- output projection GEMM (fp32 out) ----------------
__global__ __launch_bounds__(256) void out_gemm(const bfu* __restrict__ Ab,
                                                const bfu* __restrict__ wob,
                                                float* __restrict__ out)
{
  __shared__ bfu aT[128 * 64], bT[128 * 64];
  floatx4 acc[4][4] = {};
  const int m0 = blockIdx.y * 128, n0 = blockIdx.x * 128;
  gemm_core(Ab, wob, aT, bT, m0, n0, acc);

  const int lane = threadIdx.x & 63;
  const int g = lane >> 4, i16 = lane & 15;
  const int w = threadIdx.x >> 6, wm = w >> 1, wn = w & 1;
#pragma unroll
  for (int fm = 0; fm < 4; ++fm)
#pragma unroll
    for (int fn = 0; fn < 4; ++fn) {
      int col = n0 + wn * 64 + fn * 16 + i16;
#pragma unroll
      for (int r = 0; r < 4; ++r) {
        int mrow = m0 + wm * 64 + fm * 16 + g * 4 + r;
        out[(size_t)mrow * D_ + col] = acc[fm][fn][r];
      }
    }
}

// ---------------- launch ----------------
extern "C" void kernel_launch(void* const* d_in, const int* in_sizes, int n_in,
                              void* d_out, int out_size, void* d_ws, size_t ws_size,
                              hipStream_t stream)
{
  const float* x  = (const float*)d_in[0];
  const float* wq = (const float*)d_in[1];
  const float* wk = (const float*)d_in[2];
  const float* wv = (const float*)d_in[3];
  const float* wo = (const float*)d_in[4];

  bfu* xb  = (bfu*)d_ws;                          // [8192][1024]
  bfu* wqb = xb  + (size_t)M_ * D_;
  bfu* wkb = wqb + (size_t)D_ * D_;
  bfu* wvb = wkb + (size_t)D_ * D_;
  bfu* wob = wvb + (size_t)D_ * D_;
  bfu* Qd  = wob + (size_t)D_ * D_;               // [bh][s][dk]
  bfu* Kd  = Qd  + (size_t)M_ * D_;               // [bh][s][dk]
  bfu* Vtd = Kd  + (size_t)M_ * D_;               // [bh][dk][s]
  bfu* Ad  = Vtd + (size_t)M_ * D_;               // attn out bf16 [b][s][d]

  const int thr = 256;
  cvt_f32_bf16<<<(M_ * D_ / 4 + thr - 1) / thr, thr, 0, stream>>>(x, xb, M_ * D_);
  cvt_f32_bf16<<<(D_ * D_ / 4 + thr - 1) / thr, thr, 0, stream>>>(wq, wqb, D_ * D_);
  cvt_f32_bf16<<<(D_ * D_ / 4 + thr - 1) / thr, thr, 0, stream>>>(wk, wkb, D_ * D_);
  cvt_f32_bf16<<<(D_ * D_ / 4 + thr - 1) / thr, thr, 0, stream>>>(wv, wvb, D_ * D_);
  cvt_f32_bf16<<<(D_ * D_ / 4 + thr - 1) / thr, thr, 0, stream>>>(wo, wob, D_ * D_);

  proj_gemm<<<dim3(8, 64, 3), 256, 0, stream>>>(xb, wqb, wkb, wvb, Qd, Kd, Vtd);
  attn_kernel<<<dim3(S_ / 64, B_ * H_), 256, 0, stream>>>(Qd, Kd, Vtd, Ad);
  out_gemm<<<dim3(8, 64), 256, 0, stream>>>(Ad, wob, (float*)d_out);
}

// Round 5
// 482.649 us; speedup vs baseline: 1.6600x; 1.6600x over previous
//
#include <hip/hip_runtime.h>
#include <stdint.h>

// Problem constants
#define B_ 4
#define S_ 2048
#define D_ 1024
#define H_ 16
#define DK_ 64
#define M_ (B_*S_)   // 8192 rows

typedef __attribute__((ext_vector_type(8))) short bhalf8;   // 8 x bf16 (4 VGPRs)
typedef __attribute__((ext_vector_type(4))) short bhalf4;   // 4 x bf16 (2 VGPRs)
typedef __attribute__((ext_vector_type(4))) float floatx4;  // MFMA accumulator
typedef unsigned short bfu;
typedef unsigned int u32;

// fp32 -> bf16 (RNE), branchless
__device__ __forceinline__ bfu f2bf(float f) {
  union { float f; u32 u; } v; v.f = f;
  u32 r = v.u + 0x7FFFu + ((v.u >> 16) & 1u);
  return (bfu)(r >> 16);
}

// pack two fp32 -> one u32 of 2 bf16 (RNE), via v_perm byte select
__device__ __forceinline__ u32 packbf(float a, float b) {
  union { float f; u32 u; } x, y; x.f = a; y.f = b;
  u32 ra = x.u + 0x7FFFu + ((x.u >> 16) & 1u);
  u32 rb = y.u + 0x7FFFu + ((y.u >> 16) & 1u);
  return __builtin_amdgcn_perm(rb, ra, 0x07060302u);
}

// ---------------- conversion kernel ----------------
__global__ void cvt_f32_bf16(const float* __restrict__ src, bfu* __restrict__ dst, int n) {
  int i = (blockIdx.x * blockDim.x + threadIdx.x) * 4;
  if (i >= n) return;
  float4 v = *(const float4*)(src + i);
  ushort4 o;
  o.x = f2bf(v.x); o.y = f2bf(v.y); o.z = f2bf(v.z); o.w = f2bf(v.w);
  *(ushort4*)(dst + i) = o;
}

// ---------------- GEMM core: C[128x128] = A[M,K] * B[N,K]^T (both K-contig bf16) ----------------
__device__ __forceinline__ void gemm_core(const bfu* __restrict__ A,
                                          const bfu* __restrict__ Bw,
                                          bfu* aT, bfu* bT,
                                          int m0, int n0,
                                          floatx4 (&acc)[4][4])
{
  const int tid  = threadIdx.x;
  const int lane = tid & 63;
  const int g    = lane >> 4;
  const int i16  = lane & 15;
  const int w    = tid >> 6;
  const int wm   = w >> 1, wn = w & 1;

  for (int k0 = 0; k0 < D_; k0 += 64) {
    bhalf8 ra[4], rb[4];
#pragma unroll
    for (int l = 0; l < 4; ++l) {
      int e = (l * 256 + tid) * 8;
      int row = e >> 6, col = e & 63;
      ra[l] = *(const bhalf8*)(A  + (size_t)(m0 + row) * D_ + k0 + col);
      rb[l] = *(const bhalf8*)(Bw + (size_t)(n0 + row) * D_ + k0 + col);
    }
    __syncthreads();
#pragma unroll
    for (int l = 0; l < 4; ++l) {
      int e = (l * 256 + tid) * 8;
      int row = e >> 6, colb = (e & 63) * 2;
      int sw = colb ^ ((row & 7) << 4);
      *(bhalf8*)((char*)aT + row * 128 + sw) = ra[l];
      *(bhalf8*)((char*)bT + row * 128 + sw) = rb[l];
    }
    __syncthreads();
#pragma unroll
    for (int kb = 0; kb < 2; ++kb) {
      bhalf8 af[4], bf[4];
#pragma unroll
      for (int f = 0; f < 4; ++f) {
        int arow = wm * 64 + f * 16 + i16;
        af[f] = *(const bhalf8*)((const char*)aT + arow * 128 + ((kb * 64 + g * 16) ^ ((arow & 7) << 4)));
        int brow = wn * 64 + f * 16 + i16;
        bf[f] = *(const bhalf8*)((const char*)bT + brow * 128 + ((kb * 64 + g * 16) ^ ((brow & 7) << 4)));
      }
#pragma unroll
      for (int fm = 0; fm < 4; ++fm)
#pragma unroll
        for (int fn = 0; fn < 4; ++fn)
          acc[fm][fn] = __builtin_amdgcn_mfma_f32_16x16x32_bf16(af[fm], bf[fn], acc[fm][fn], 0, 0, 0);
    }
  }
}

// ---------------- QKV projection GEMM ----------------
__global__ __launch_bounds__(256) void proj_gemm(const bfu* __restrict__ xb,
                                                 const bfu* __restrict__ wqb,
                                                 const bfu* __restrict__ wkb,
                                                 const bfu* __restrict__ wvb,
                                                 bfu* __restrict__ Qd,
                                                 bfu* __restrict__ Kd,
                                                 bfu* __restrict__ Vtd)
{
  __shared__ bfu aT[128 * 64], bT[128 * 64];
  const int z = blockIdx.z;
  const bfu* Bw = (z == 0) ? wqb : (z == 1) ? wkb : wvb;
  bfu* dst      = (z == 0) ? Qd  : (z == 1) ? Kd  : Vtd;

  floatx4 acc[4][4] = {};
  const int m0 = blockIdx.y * 128, n0 = blockIdx.x * 128;
  gemm_core(xb, Bw, aT, bT, m0, n0, acc);

  const int lane = threadIdx.x & 63;
  const int g = lane >> 4, i16 = lane & 15;
  const int w = threadIdx.x >> 6, wm = w >> 1, wn = w & 1;
#pragma unroll
  for (int fm = 0; fm < 4; ++fm) {
#pragma unroll
    for (int fn = 0; fn < 4; ++fn) {
      int col = n0 + wn * 64 + fn * 16 + i16;
      int h = col >> 6, dk = col & 63;
#pragma unroll
      for (int r = 0; r < 4; ++r) {
        int mrow = m0 + wm * 64 + fm * 16 + g * 4 + r;
        int b = mrow >> 11, s = mrow & (S_ - 1);
        size_t idx = (z == 2)
            ? ((size_t)((b * H_ + h) * DK_ + dk)) * S_ + s    // V^T
            : ((size_t)((b * H_ + h) * S_ + s)) * DK_ + dk;   // Q,K
        dst[idx] = f2bf(acc[fm][fn][r]);
      }
    }
  }
}

// ---------------- flash attention (causal), swapped-operand, register-prefetch ----------------
// grid (B*H, S/128): blockIdx.x = bh (XCD-local K/V reuse), blockIdx.y = pair.
// Each block runs two q-tiles {pair, 31-pair} sequentially -> uniform 33 kv-tiles (no tail).
// 4 independent waves; wave w owns q rows [qtile*64+16w, +16).
// S^T = mfma(K,Q): per-lane q (i16) -> in-register softmax (2 shfl). PV: O^T = V^T @ P^T
// via mfma_16x16x16bf16_1k, P^T straight from registers.
// K double-buffered in registers (prefetch t+1 before compute t); V issued early each tile.
struct KTile { bhalf8 f[8]; };
struct VTile { bhalf4 f[16]; };

__device__ __forceinline__ void load_k(const bfu* __restrict__ Kb, int kv0, int i16, int g, KTile& kt) {
#pragma unroll
  for (int cb = 0; cb < 4; ++cb)
#pragma unroll
    for (int kb = 0; kb < 2; ++kb)
      kt.f[cb * 2 + kb] = *(const bhalf8*)(Kb + (size_t)(kv0 + cb * 16 + i16) * DK_ + kb * 32 + g * 8);
}
__device__ __forceinline__ void load_v(const bfu* __restrict__ Vb, int kv0, int i16, int g, VTile& vt) {
#pragma unroll
  for (int da = 0; da < 4; ++da)
#pragma unroll
    for (int cb = 0; cb < 4; ++cb)
      vt.f[da * 4 + cb] = *(const bhalf4*)(Vb + (size_t)(da * 16 + i16) * S_ + kv0 + cb * 16 + g * 4);
}

__global__ __launch_bounds__(256) void attn_kernel(const bfu* __restrict__ Q,
                                                   const bfu* __restrict__ Kc,
                                                   const bfu* __restrict__ Vt,
                                                   bfu* __restrict__ Oc)
{
  const int tid = threadIdx.x;
  const int lane = tid & 63;
  const int w = tid >> 6;
  const int g = lane >> 4, i16 = lane & 15;
  const int bh = blockIdx.x;          // same bh -> same wgid%8 -> same XCD (L2 K/V reuse)
  const int pair = blockIdx.y;        // 0..15

  const bfu* Qb = Q  + (size_t)bh * S_ * DK_;
  const bfu* Kb = Kc + (size_t)bh * S_ * DK_;
  const bfu* Vb = Vt + (size_t)bh * DK_ * S_;
  const int b = bh >> 4, h = bh & 15;

  const float C2 = 0.125f * 1.44269504f;   // dk^-0.5 * log2(e) folded

  for (int pass = 0; pass < 2; ++pass) {
    const int qtile = (pass == 0) ? pair : (31 - pair);
    const int qr = qtile * 64 + w * 16;
    const int nt = qtile + 1;

    // Q B-frags (col=q=i16, k=dk)
    bhalf8 qa[2];
#pragma unroll
    for (int kb = 0; kb < 2; ++kb)
      qa[kb] = *(const bhalf8*)(Qb + (size_t)(qr + i16) * DK_ + kb * 32 + g * 8);

    floatx4 ot[4] = {};          // O^T: col=q=i16, row=dk = da*16 + g*4+r
    float mraw = -3.0e38f;
    float mC2  = -1.0e37f;
    float lp   = 0.f;

    KTile k0, k1; VTile vt;
    load_k(Kb, 0, i16, g, k0);

    auto compute = [&](int t, const KTile& kt, const VTile& vtt) {
      const int kv0 = t * 64;
      // ---- S^T = K @ Q^T ----
      floatx4 sa[4] = {};
#pragma unroll
      for (int cb = 0; cb < 4; ++cb) {
        sa[cb] = __builtin_amdgcn_mfma_f32_16x16x32_bf16(kt.f[cb * 2 + 0], qa[0], sa[cb], 0, 0, 0);
        sa[cb] = __builtin_amdgcn_mfma_f32_16x16x32_bf16(kt.f[cb * 2 + 1], qa[1], sa[cb], 0, 0, 0);
      }
      // ---- causal mask (only last tile partial; wave-uniform branch) ----
      if (t == nt - 1) {
#pragma unroll
        for (int cb = 0; cb < 4; ++cb)
#pragma unroll
          for (int r = 0; r < 4; ++r)
            if (kv0 + cb * 16 + g * 4 + r > qr + i16) sa[cb][r] = -3.0e38f;
      }
      // ---- row max: 16 in-lane + 2 shfl ----
      float pm = -3.0e38f;
#pragma unroll
      for (int cb = 0; cb < 4; ++cb)
#pragma unroll
        for (int r = 0; r < 4; ++r)
          pm = fmaxf(pm, sa[cb][r]);
      pm = fmaxf(pm, __shfl_xor(pm, 16));
      pm = fmaxf(pm, __shfl_xor(pm, 32));
      const float mn = fmaxf(mraw, pm);
      const float mnC2 = mn * C2;
      const float al = exp2f(mC2 - mnC2);
      mraw = mn; mC2 = mnC2;
      const float nm = -mnC2;
      // ---- P = exp2(S*C2 - mn*C2); pack to bf16 ----
      u32 pk[8];
      float ps = 0.f;
#pragma unroll
      for (int cb = 0; cb < 4; ++cb) {
        float p0 = exp2f(__builtin_fmaf(sa[cb][0], C2, nm));
        float p1 = exp2f(__builtin_fmaf(sa[cb][1], C2, nm));
        float p2 = exp2f(__builtin_fmaf(sa[cb][2], C2, nm));
        float p3 = exp2f(__builtin_fmaf(sa[cb][3], C2, nm));
        ps += (p0 + p1) + (p2 + p3);
        pk[cb * 2]     = packbf(p0, p1);
        pk[cb * 2 + 1] = packbf(p2, p3);
      }
      lp = lp * al + ps;
#pragma unroll
      for (int da = 0; da < 4; ++da)
#pragma unroll
        for (int r = 0; r < 4; ++r)
          ot[da][r] *= al;
      // ---- O^T += V^T @ P^T ----
#pragma unroll
      for (int da = 0; da < 4; ++da) {
#pragma unroll
        for (int cb = 0; cb < 4; ++cb) {
          union { u32 u[2]; bhalf4 h; } pu;
          pu.u[0] = pk[cb * 2]; pu.u[1] = pk[cb * 2 + 1];
          ot[da] = __builtin_amdgcn_mfma_f32_16x16x16bf16_1k(vtt.f[da * 4 + cb], pu.h, ot[da], 0, 0, 0);
        }
      }
    };

    for (int t = 0; t < nt; ++t) {
      load_v(Vb, t * 64, i16, g, vt);            // needed late in compute(t)
      if ((t & 1) == 0) {
        if (t + 1 < nt) load_k(Kb, (t + 1) * 64, i16, g, k1);   // prefetch next K
        compute(t, k0, vt);
      } else {
        if (t + 1 < nt) load_k(Kb, (t + 1) * 64, i16, g, k0);
        compute(t, k1, vt);
      }
    }

    // ---- epilogue: reduce l, divide, store ----
    float lt = lp;
    lt += __shfl_xor(lt, 16);
    lt += __shfl_xor(lt, 32);
    const float rl = 1.0f / lt;
    const size_t rowbase = (size_t)(b * S_ + qr + i16) * D_ + h * 64;
#pragma unroll
    for (int da = 0; da < 4; ++da) {
      ushort4 ov;
      ov.x = f2bf(ot[da][0] * rl);
      ov.y = f2bf(ot[da][1] * rl);
      ov.z = f2bf(ot[da][2] * rl);
      ov.w = f2bf(ot[da][3] * rl);
      *(ushort4*)(Oc + rowbase + da * 16 + g * 4) = ov;
    }
  }
}

// ---------------- output projection GEMM (fp32 out) ----------------
__global__ __launch_bounds__(256) void out_gemm(const bfu* __restrict__ Ab,
                                                const bfu* __restrict__ wob,
                                                float* __restrict__ out)
{
  __shared__ bfu aT[128 * 64], bT[128 * 64];
  floatx4 acc[4][4] = {};
  const int m0 = blockIdx.y * 128, n0 = blockIdx.x * 128;
  gemm_core(Ab, wob, aT, bT, m0, n0, acc);

  const int lane = threadIdx.x & 63;
  const int g = lane >> 4, i16 = lane & 15;
  const int w = threadIdx.x >> 6, wm = w >> 1, wn = w & 1;
#pragma unroll
  for (int fm = 0; fm < 4; ++fm)
#pragma unroll
    for (int fn = 0; fn < 4; ++fn) {
      int col = n0 + wn * 64 + fn * 16 + i16;
#pragma unroll
      for (int r = 0; r < 4; ++r) {
        int mrow = m0 + wm * 64 + fm * 16 + g * 4 + r;
        out[(size_t)mrow * D_ + col] = acc[fm][fn][r];
      }
    }
}

// ---------------- launch ----------------
extern "C" void kernel_launch(void* const* d_in, const int* in_sizes, int n_in,
                              void* d_out, int out_size, void* d_ws, size_t ws_size,
                              hipStream_t stream)
{
  const float* x  = (const float*)d_in[0];
  const float* wq = (const float*)d_in[1];
  const float* wk = (const float*)d_in[2];
  const float* wv = (const float*)d_in[3];
  const float* wo = (const float*)d_in[4];

  bfu* xb  = (bfu*)d_ws;                          // [8192][1024]
  bfu* wqb = xb  + (size_t)M_ * D_;
  bfu* wkb = wqb + (size_t)D_ * D_;
  bfu* wvb = wkb + (size_t)D_ * D_;
  bfu* wob = wvb + (size_t)D_ * D_;
  bfu* Qd  = wob + (size_t)D_ * D_;               // [bh][s][dk]
  bfu* Kd  = Qd  + (size_t)M_ * D_;               // [bh][s][dk]
  bfu* Vtd = Kd  + (size_t)M_ * D_;               // [bh][dk][s]
  bfu* Ad  = Vtd + (size_t)M_ * D_;               // attn out bf16 [b][s][d]

  const int thr = 256;
  cvt_f32_bf16<<<(M_ * D_ / 4 + thr - 1) / thr, thr, 0, stream>>>(x, xb, M_ * D_);
  cvt_f32_bf16<<<(D_ * D_ / 4 + thr - 1) / thr, thr, 0, stream>>>(wq, wqb, D_ * D_);
  cvt_f32_bf16<<<(D_ * D_ / 4 + thr - 1) / thr, thr, 0, stream>>>(wk, wkb, D_ * D_);
  cvt_f32_bf16<<<(D_ * D_ / 4 + thr - 1) / thr, thr, 0, stream>>>(wv, wvb, D_ * D_);
  cvt_f32_bf16<<<(D_ * D_ / 4 + thr - 1) / thr, thr, 0, stream>>>(wo, wob, D_ * D_);

  proj_gemm<<<dim3(8, 64, 3), 256, 0, stream>>>(xb, wqb, wkb, wvb, Qd, Kd, Vtd);
  attn_kernel<<<dim3(B_ * H_, S_ / 128), 256, 0, stream>>>(Qd, Kd, Vtd, Ad);
  out_gemm<<<dim3(8, 64), 256, 0, stream>>>(Ad, wob, (float*)d_out);
}

// Round 6
// 242.004 us; speedup vs baseline: 3.3107x; 1.9944x over previous
//
#include <hip/hip_runtime.h>
#include <stdint.h>

// Problem constants
#define B_ 4
#define S_ 2048
#define D_ 1024
#define H_ 16
#define DK_ 64
#define M_ (B_*S_)   // 8192 rows

typedef __attribute__((ext_vector_type(8))) short bhalf8;   // 8 x bf16 (4 VGPRs)
typedef __attribute__((ext_vector_type(4))) short bhalf4;   // 4 x bf16 (2 VGPRs)
typedef __attribute__((ext_vector_type(4))) float floatx4;  // MFMA accumulator
typedef unsigned short bfu;
typedef unsigned int u32;

// fp32 -> bf16 (RNE), branchless
__device__ __forceinline__ bfu f2bf(float f) {
  union { float f; u32 u; } v; v.f = f;
  u32 r = v.u + 0x7FFFu + ((v.u >> 16) & 1u);
  return (bfu)(r >> 16);
}

// pack two fp32 -> one u32 of 2 bf16 (RNE), via v_perm byte select
__device__ __forceinline__ u32 packbf(float a, float b) {
  union { float f; u32 u; } x, y; x.f = a; y.f = b;
  u32 ra = x.u + 0x7FFFu + ((x.u >> 16) & 1u);
  u32 rb = y.u + 0x7FFFu + ((y.u >> 16) & 1u);
  return __builtin_amdgcn_perm(rb, ra, 0x07060302u);
}

// ---------------- conversion kernel ----------------
__global__ void cvt_f32_bf16(const float* __restrict__ src, bfu* __restrict__ dst, int n) {
  int i = (blockIdx.x * blockDim.x + threadIdx.x) * 4;
  if (i >= n) return;
  float4 v = *(const float4*)(src + i);
  ushort4 o;
  o.x = f2bf(v.x); o.y = f2bf(v.y); o.z = f2bf(v.z); o.w = f2bf(v.w);
  *(ushort4*)(dst + i) = o;
}

// ---------------- GEMM core: C[128x128] = A[M,K] * B[N,K]^T (both K-contig bf16) ----------------
__device__ __forceinline__ void gemm_core(const bfu* __restrict__ A,
                                          const bfu* __restrict__ Bw,
                                          bfu* aT, bfu* bT,
                                          int m0, int n0,
                                          floatx4 (&acc)[4][4])
{
  const int tid  = threadIdx.x;
  const int lane = tid & 63;
  const int g    = lane >> 4;
  const int i16  = lane & 15;
  const int w    = tid >> 6;
  const int wm   = w >> 1, wn = w & 1;

  for (int k0 = 0; k0 < D_; k0 += 64) {
    bhalf8 ra[4], rb[4];
#pragma unroll
    for (int l = 0; l < 4; ++l) {
      int e = (l * 256 + tid) * 8;
      int row = e >> 6, col = e & 63;
      ra[l] = *(const bhalf8*)(A  + (size_t)(m0 + row) * D_ + k0 + col);
      rb[l] = *(const bhalf8*)(Bw + (size_t)(n0 + row) * D_ + k0 + col);
    }
    __syncthreads();
#pragma unroll
    for (int l = 0; l < 4; ++l) {
      int e = (l * 256 + tid) * 8;
      int row = e >> 6, colb = (e & 63) * 2;
      int sw = colb ^ ((row & 7) << 4);
      *(bhalf8*)((char*)aT + row * 128 + sw) = ra[l];
      *(bhalf8*)((char*)bT + row * 128 + sw) = rb[l];
    }
    __syncthreads();
#pragma unroll
    for (int kb = 0; kb < 2; ++kb) {
      bhalf8 af[4], bf[4];
#pragma unroll
      for (int f = 0; f < 4; ++f) {
        int arow = wm * 64 + f * 16 + i16;
        af[f] = *(const bhalf8*)((const char*)aT + arow * 128 + ((kb * 64 + g * 16) ^ ((arow & 7) << 4)));
        int brow = wn * 64 + f * 16 + i16;
        bf[f] = *(const bhalf8*)((const char*)bT + brow * 128 + ((kb * 64 + g * 16) ^ ((brow & 7) << 4)));
      }
#pragma unroll
      for (int fm = 0; fm < 4; ++fm)
#pragma unroll
        for (int fn = 0; fn < 4; ++fn)
          acc[fm][fn] = __builtin_amdgcn_mfma_f32_16x16x32_bf16(af[fm], bf[fn], acc[fm][fn], 0, 0, 0);
    }
  }
}

// ---------------- QKV projection GEMM ----------------
__global__ __launch_bounds__(256) void proj_gemm(const bfu* __restrict__ xb,
                                                 const bfu* __restrict__ wqb,
                                                 const bfu* __restrict__ wkb,
                                                 const bfu* __restrict__ wvb,
                                                 bfu* __restrict__ Qd,
                                                 bfu* __restrict__ Kd,
                                                 bfu* __restrict__ Vtd)
{
  __shared__ bfu aT[128 * 64], bT[128 * 64];
  const int z = blockIdx.z;
  const bfu* Bw = (z == 0) ? wqb : (z == 1) ? wkb : wvb;
  bfu* dst      = (z == 0) ? Qd  : (z == 1) ? Kd  : Vtd;

  floatx4 acc[4][4] = {};
  const int m0 = blockIdx.y * 128, n0 = blockIdx.x * 128;
  gemm_core(xb, Bw, aT, bT, m0, n0, acc);

  const int lane = threadIdx.x & 63;
  const int g = lane >> 4, i16 = lane & 15;
  const int w = threadIdx.x >> 6, wm = w >> 1, wn = w & 1;
#pragma unroll
  for (int fm = 0; fm < 4; ++fm) {
#pragma unroll
    for (int fn = 0; fn < 4; ++fn) {
      int col = n0 + wn * 64 + fn * 16 + i16;
      int h = col >> 6, dk = col & 63;
#pragma unroll
      for (int r = 0; r < 4; ++r) {
        int mrow = m0 + wm * 64 + fm * 16 + g * 4 + r;
        int b = mrow >> 11, s = mrow & (S_ - 1);
        size_t idx = (z == 2)
            ? ((size_t)((b * H_ + h) * DK_ + dk)) * S_ + s    // V^T
            : ((size_t)((b * H_ + h) * S_ + s)) * DK_ + dk;   // Q,K
        dst[idx] = f2bf(acc[fm][fn][r]);
      }
    }
  }
}

// ---------------- flash attention (causal): LDS-staged K/V, double-buffered ----------------
// grid (B*H, S/128): blockIdx.x = bh (XCD L2 reuse), blockIdx.y = pair.
// Block runs q-tiles {pair, 31-pair} -> uniform 33 kv-tiles. 4 waves, wave w owns q rows
// [qtile*64+16w, +16). Per kv-tile the BLOCK stages K(64x64)+V^T(64x64) bf16 into LDS once
// (waves 0-1 stage K, 2-3 stage V; 16B/lane coalesced; XOR-swizzled writes), double-buffered:
// stage_load(t+1) global->regs issued before compute(t) (latency hides under MFMA+softmax),
// stage_write to idle buffer after, one barrier per tile.
// S^T = mfma(K,Q) keeps softmax per-lane (2 shfl); PV: O^T = V^T @ P^T from registers.
struct Stage { bhalf8 r[4]; };

__device__ __forceinline__ void stage_load(const bfu* __restrict__ Kb,
                                           const bfu* __restrict__ Vb,
                                           int kv0, int w, int lane, Stage& st) {
#pragma unroll
  for (int i = 0; i < 4; ++i) {
    const int o = w * 4096 + i * 1024 + lane * 16;   // byte offset in 16KB tile image
    const bfu* src;
    if (o < 8192) {                                  // K region (waves 0,1) — wave-uniform
      const int row = o >> 7, colb = o & 127;
      src = Kb + (size_t)(kv0 + row) * DK_ + (colb >> 1);
    } else {                                         // V region (waves 2,3)
      const int o2 = o - 8192;
      const int row = o2 >> 7, colb = o2 & 127;
      src = Vb + (size_t)row * S_ + kv0 + (colb >> 1);
    }
    st.r[i] = *(const bhalf8*)src;
  }
}

__device__ __forceinline__ void stage_write(char* buf, int w, int lane, const Stage& st) {
#pragma unroll
  for (int i = 0; i < 4; ++i) {
    const int o = w * 4096 + i * 1024 + lane * 16;
    const int reg = o & 8192;
    const int row = (o >> 7) & 63;
    const int colb = o & 127;
    *(bhalf8*)(buf + reg + row * 128 + (colb ^ ((row & 7) << 4))) = st.r[i];
  }
}

__global__ __launch_bounds__(256) void attn_kernel(const bfu* __restrict__ Q,
                                                   const bfu* __restrict__ Kc,
                                                   const bfu* __restrict__ Vt,
                                                   bfu* __restrict__ Oc)
{
  __shared__ char smem[2 * 16384];
  const int tid = threadIdx.x;
  const int lane = tid & 63;
  const int w = tid >> 6;
  const int g = lane >> 4, i16 = lane & 15;
  const int sw = (i16 & 7) << 4;       // per-lane read swizzle
  const int bh = blockIdx.x;
  const int pair = blockIdx.y;         // 0..15

  const bfu* Qb = Q  + (size_t)bh * S_ * DK_;
  const bfu* Kb = Kc + (size_t)bh * S_ * DK_;
  const bfu* Vb = Vt + (size_t)bh * DK_ * S_;
  const int b = bh >> 4, h = bh & 15;

  const float C2 = 0.125f * 1.44269504f;   // dk^-0.5 * log2(e)

  for (int pass = 0; pass < 2; ++pass) {
    const int qtile = (pass == 0) ? pair : (31 - pair);
    const int qr = qtile * 64 + w * 16;
    const int nt = qtile + 1;

    // Q B-frags (col=q=i16, k=dk)
    bhalf8 qa[2];
#pragma unroll
    for (int kb = 0; kb < 2; ++kb)
      qa[kb] = *(const bhalf8*)(Qb + (size_t)(qr + i16) * DK_ + kb * 32 + g * 8);

    floatx4 ot[4] = {};          // O^T: col=q=i16, row=dk = da*16 + g*4+r
    float mraw = -3.0e38f;
    float mC2  = -1.0e37f;
    float lp   = 0.f;

    Stage st;
    stage_load(Kb, Vb, 0, w, lane, st);
    stage_write(smem, w, lane, st);
    __syncthreads();

    int cur = 0;
    for (int t = 0; t < nt; ++t) {
      char* rb = smem + cur * 16384;
      char* wb = smem + (cur ^ 1) * 16384;
      const bool more = (t + 1 < nt);
      if (more) stage_load(Kb, Vb, (t + 1) * 64, w, lane, st);

      const int kv0 = t * 64;
      // ---- S^T = K @ Q^T (K frags from LDS) ----
      floatx4 sa[4] = {};
#pragma unroll
      for (int cb = 0; cb < 4; ++cb) {
        const int krow = cb * 16 + i16;
        bhalf8 kf0 = *(const bhalf8*)(rb + krow * 128 + ((g * 16) ^ sw));
        bhalf8 kf1 = *(const bhalf8*)(rb + krow * 128 + ((64 + g * 16) ^ sw));
        sa[cb] = __builtin_amdgcn_mfma_f32_16x16x32_bf16(kf0, qa[0], sa[cb], 0, 0, 0);
        sa[cb] = __builtin_amdgcn_mfma_f32_16x16x32_bf16(kf1, qa[1], sa[cb], 0, 0, 0);
      }
      // ---- causal mask (only last tile partial; wave-uniform branch) ----
      if (t == nt - 1) {
#pragma unroll
        for (int cb = 0; cb < 4; ++cb)
#pragma unroll
          for (int r = 0; r < 4; ++r)
            if (kv0 + cb * 16 + g * 4 + r > qr + i16) sa[cb][r] = -3.0e38f;
      }
      // ---- row max: 16 in-lane + 2 shfl ----
      float pm = -3.0e38f;
#pragma unroll
      for (int cb = 0; cb < 4; ++cb)
#pragma unroll
        for (int r = 0; r < 4; ++r)
          pm = fmaxf(pm, sa[cb][r]);
      pm = fmaxf(pm, __shfl_xor(pm, 16));
      pm = fmaxf(pm, __shfl_xor(pm, 32));
      const float mn = fmaxf(mraw, pm);
      const float mnC2 = mn * C2;
      const float al = exp2f(mC2 - mnC2);
      mraw = mn; mC2 = mnC2;
      const float nm = -mnC2;
      // ---- P = exp2(S*C2 - mn*C2); pack to bf16 ----
      u32 pk[8];
      float ps = 0.f;
#pragma unroll
      for (int cb = 0; cb < 4; ++cb) {
        float p0 = exp2f(__builtin_fmaf(sa[cb][0], C2, nm));
        float p1 = exp2f(__builtin_fmaf(sa[cb][1], C2, nm));
        float p2 = exp2f(__builtin_fmaf(sa[cb][2], C2, nm));
        float p3 = exp2f(__builtin_fmaf(sa[cb][3], C2, nm));
        ps += (p0 + p1) + (p2 + p3);
        pk[cb * 2]     = packbf(p0, p1);
        pk[cb * 2 + 1] = packbf(p2, p3);
      }
      lp = lp * al + ps;
#pragma unroll
      for (int da = 0; da < 4; ++da)
#pragma unroll
        for (int r = 0; r < 4; ++r)
          ot[da][r] *= al;
      // ---- O^T += V^T @ P^T (V frags from LDS) ----
      const char* vbuf = rb + 8192;
#pragma unroll
      for (int da = 0; da < 4; ++da) {
        const int vrow = da * 16 + i16;
#pragma unroll
        for (int cb = 0; cb < 4; ++cb) {
          bhalf4 vf = *(const bhalf4*)(vbuf + vrow * 128 + ((cb * 32 + g * 8) ^ sw));
          union { u32 u[2]; bhalf4 h; } pu;
          pu.u[0] = pk[cb * 2]; pu.u[1] = pk[cb * 2 + 1];
          ot[da] = __builtin_amdgcn_mfma_f32_16x16x16bf16_1k(vf, pu.h, ot[da], 0, 0, 0);
        }
      }

      if (more) stage_write(wb, w, lane, st);
      __syncthreads();
      cur ^= 1;
    }

    // ---- epilogue: reduce l, divide, store ----
    float lt = lp;
    lt += __shfl_xor(lt, 16);
    lt += __shfl_xor(lt, 32);
    const float rl = 1.0f / lt;
    const size_t rowbase = (size_t)(b * S_ + qr + i16) * D_ + h * 64;
#pragma unroll
    for (int da = 0; da < 4; ++da) {
      ushort4 ov;
      ov.x = f2bf(ot[da][0] * rl);
      ov.y = f2bf(ot[da][1] * rl);
      ov.z = f2bf(ot[da][2] * rl);
      ov.w = f2bf(ot[da][3] * rl);
      *(ushort4*)(Oc + rowbase + da * 16 + g * 4) = ov;
    }
  }
}

// ---------------- output projection GEMM (fp32 out) ----------------
__global__ __launch_bounds__(256) void out_gemm(const bfu* __restrict__ Ab,
                                                const bfu* __restrict__ wob,
                                                float* __restrict__ out)
{
  __shared__ bfu aT[128 * 64], bT[128 * 64];
  floatx4 acc[4][4] = {};
  const int m0 = blockIdx.y * 128, n0 = blockIdx.x * 128;
  gemm_core(Ab, wob, aT, bT, m0, n0, acc);

  const int lane = threadIdx.x & 63;
  const int g = lane >> 4, i16 = lane & 15;
  const int w = threadIdx.x >> 6, wm = w >> 1, wn = w & 1;
#pragma unroll
  for (int fm = 0; fm < 4; ++fm)
#pragma unroll
    for (int fn = 0; fn < 4; ++fn) {
      int col = n0 + wn * 64 + fn * 16 + i16;
#pragma unroll
      for (int r = 0; r < 4; ++r) {
        int mrow = m0 + wm * 64 + fm * 16 + g * 4 + r;
        out[(size_t)mrow * D_ + col] = acc[fm][fn][r];
      }
    }
}

// ---------------- launch ----------------
extern "C" void kernel_launch(void* const* d_in, const int* in_sizes, int n_in,
                              void* d_out, int out_size, void* d_ws, size_t ws_size,
                              hipStream_t stream)
{
  const float* x  = (const float*)d_in[0];
  const float* wq = (const float*)d_in[1];
  const float* wk = (const float*)d_in[2];
  const float* wv = (const float*)d_in[3];
  const float* wo = (const float*)d_in[4];

  bfu* xb  = (bfu*)d_ws;                          // [8192][1024]
  bfu* wqb = xb  + (size_t)M_ * D_;
  bfu* wkb = wqb + (size_t)D_ * D_;
  bfu* wvb = wkb + (size_t)D_ * D_;
  bfu* wob = wvb + (size_t)D_ * D_;
  bfu* Qd  = wob + (size_t)D_ * D_;               // [bh][s][dk]
  bfu* Kd  = Qd  + (size_t)M_ * D_;               // [bh][s][dk]
  bfu* Vtd = Kd  + (size_t)M_ * D_;               // [bh][dk][s]
  bfu* Ad  = Vtd + (size_t)M_ * D_;               // attn out bf16 [b][s][d]

  const int thr = 256;
  cvt_f32_bf16<<<(M_ * D_ / 4 + thr - 1) / thr, thr, 0, stream>>>(x, xb, M_ * D_);
  cvt_f32_bf16<<<(D_ * D_ / 4 + thr - 1) / thr, thr, 0, stream>>>(wq, wqb, D_ * D_);
  cvt_f32_bf16<<<(D_ * D_ / 4 + thr - 1) / thr, thr, 0, stream>>>(wk, wkb, D_ * D_);
  cvt_f32_bf16<<<(D_ * D_ / 4 + thr - 1) / thr, thr, 0, stream>>>(wv, wvb, D_ * D_);
  cvt_f32_bf16<<<(D_ * D_ / 4 + thr - 1) / thr, thr, 0, stream>>>(wo, wob, D_ * D_);

  proj_gemm<<<dim3(8, 64, 3), 256, 0, stream>>>(xb, wqb, wkb, wvb, Qd, Kd, Vtd);
  attn_kernel<<<dim3(B_ * H_, S_ / 128), 256, 0, stream>>>(Qd, Kd, Vtd, Ad);
  out_gemm<<<dim3(8, 64), 256, 0, stream>>>(Ad, wob, (float*)d_out);
}

// Round 7
// 219.918 us; speedup vs baseline: 3.6432x; 1.1004x over previous
//
#include <hip/hip_runtime.h>
#include <stdint.h>

// Problem constants
#define B_ 4
#define S_ 2048
#define D_ 1024
#define H_ 16
#define DK_ 64
#define M_ (B_*S_)   // 8192 rows

typedef __attribute__((ext_vector_type(8))) short bhalf8;   // 8 x bf16 (4 VGPRs)
typedef __attribute__((ext_vector_type(4))) short bhalf4;   // 4 x bf16 (2 VGPRs)
typedef __attribute__((ext_vector_type(4))) float floatx4;  // MFMA accumulator
typedef unsigned short bfu;
typedef unsigned int u32;

// fp32 -> bf16 (RNE), branchless
__device__ __forceinline__ bfu f2bf(float f) {
  union { float f; u32 u; } v; v.f = f;
  u32 r = v.u + 0x7FFFu + ((v.u >> 16) & 1u);
  return (bfu)(r >> 16);
}

// packed fp32x2 -> bf16x2 via HW cvt (RNE); lo16 = a, hi16 = b
__device__ __forceinline__ u32 cvtpk(float a, float b) {
  u32 r;
  asm("v_cvt_pk_bf16_f32 %0, %1, %2" : "=v"(r) : "v"(a), "v"(b));
  return r;
}

// ---------------- conversion kernel ----------------
__global__ void cvt_f32_bf16(const float* __restrict__ src, bfu* __restrict__ dst, int n) {
  int i = (blockIdx.x * blockDim.x + threadIdx.x) * 4;
  if (i >= n) return;
  float4 v = *(const float4*)(src + i);
  ushort4 o;
  o.x = f2bf(v.x); o.y = f2bf(v.y); o.z = f2bf(v.z); o.w = f2bf(v.w);
  *(ushort4*)(dst + i) = o;
}

// ---------------- GEMM core: C[128x128] = A[M,K] * B[N,K]^T (both K-contig bf16) ----------------
__device__ __forceinline__ void gemm_core(const bfu* __restrict__ A,
                                          const bfu* __restrict__ Bw,
                                          bfu* aT, bfu* bT,
                                          int m0, int n0,
                                          floatx4 (&acc)[4][4])
{
  const int tid  = threadIdx.x;
  const int lane = tid & 63;
  const int g    = lane >> 4;
  const int i16  = lane & 15;
  const int w    = tid >> 6;
  const int wm   = w >> 1, wn = w & 1;

  for (int k0 = 0; k0 < D_; k0 += 64) {
    bhalf8 ra[4], rb[4];
#pragma unroll
    for (int l = 0; l < 4; ++l) {
      int e = (l * 256 + tid) * 8;
      int row = e >> 6, col = e & 63;
      ra[l] = *(const bhalf8*)(A  + (size_t)(m0 + row) * D_ + k0 + col);
      rb[l] = *(const bhalf8*)(Bw + (size_t)(n0 + row) * D_ + k0 + col);
    }
    __syncthreads();
#pragma unroll
    for (int l = 0; l < 4; ++l) {
      int e = (l * 256 + tid) * 8;
      int row = e >> 6, colb = (e & 63) * 2;
      int sw = colb ^ ((row & 7) << 4);
      *(bhalf8*)((char*)aT + row * 128 + sw) = ra[l];
      *(bhalf8*)((char*)bT + row * 128 + sw) = rb[l];
    }
    __syncthreads();
#pragma unroll
    for (int kb = 0; kb < 2; ++kb) {
      bhalf8 af[4], bf[4];
#pragma unroll
      for (int f = 0; f < 4; ++f) {
        int arow = wm * 64 + f * 16 + i16;
        af[f] = *(const bhalf8*)((const char*)aT + arow * 128 + ((kb * 64 + g * 16) ^ ((arow & 7) << 4)));
        int brow = wn * 64 + f * 16 + i16;
        bf[f] = *(const bhalf8*)((const char*)bT + brow * 128 + ((kb * 64 + g * 16) ^ ((brow & 7) << 4)));
      }
#pragma unroll
      for (int fm = 0; fm < 4; ++fm)
#pragma unroll
        for (int fn = 0; fn < 4; ++fn)
          acc[fm][fn] = __builtin_amdgcn_mfma_f32_16x16x32_bf16(af[fm], bf[fn], acc[fm][fn], 0, 0, 0);
    }
  }
}

// ---------------- QKV projection GEMM ----------------
__global__ __launch_bounds__(256) void proj_gemm(const bfu* __restrict__ xb,
                                                 const bfu* __restrict__ wqb,
                                                 const bfu* __restrict__ wkb,
                                                 const bfu* __restrict__ wvb,
                                                 bfu* __restrict__ Qd,
                                                 bfu* __restrict__ Kd,
                                                 bfu* __restrict__ Vtd)
{
  __shared__ bfu aT[128 * 64], bT[128 * 64];
  const int z = blockIdx.z;
  const bfu* Bw = (z == 0) ? wqb : (z == 1) ? wkb : wvb;
  bfu* dst      = (z == 0) ? Qd  : (z == 1) ? Kd  : Vtd;

  floatx4 acc[4][4] = {};
  const int m0 = blockIdx.y * 128, n0 = blockIdx.x * 128;
  gemm_core(xb, Bw, aT, bT, m0, n0, acc);

  const int lane = threadIdx.x & 63;
  const int g = lane >> 4, i16 = lane & 15;
  const int w = threadIdx.x >> 6, wm = w >> 1, wn = w & 1;
#pragma unroll
  for (int fm = 0; fm < 4; ++fm) {
#pragma unroll
    for (int fn = 0; fn < 4; ++fn) {
      int col = n0 + wn * 64 + fn * 16 + i16;
      int h = col >> 6, dk = col & 63;
#pragma unroll
      for (int r = 0; r < 4; ++r) {
        int mrow = m0 + wm * 64 + fm * 16 + g * 4 + r;
        int b = mrow >> 11, s = mrow & (S_ - 1);
        size_t idx = (z == 2)
            ? ((size_t)((b * H_ + h) * DK_ + dk)) * S_ + s    // V^T
            : ((size_t)((b * H_ + h) * S_ + s)) * DK_ + dk;   // Q,K
        dst[idx] = f2bf(acc[fm][fn][r]);
      }
    }
  }
}

// ---------------- flash attention (causal): 8 waves, QBLK=128, shared dbuf LDS K/V ----------------
// grid (B*H, S/128): blockIdx.x = bh (XCD L2 locality: same bh -> wgid%8 equal), y = q-block.
// Wave w owns q rows 128y+16w..+15; waves 0-3 need 2y+1 kv tiles, 4-7 need 2y+2 (= spine, even).
// Per kv-tile the block stages K(64x64)+V^T(64x64) once (1 K + 1 V 16B load per thread),
// double-buffered with compile-time buffer offsets (2-tile unrolled loop).
// S^T = mfma(K,Q): per-lane q (i16) -> in-register softmax (2 shfl, defer-max THR=8);
// PV: O^T = V^T @ P^T via mfma_16x16x16bf16_1k, P^T packed in regs via v_cvt_pk_bf16_f32.
template<int BUF>
__device__ __forceinline__ void attn_tile(const char* smem, int t, int ntw, int qr,
                                          int koff0, int koff1, const int (&voff)[4],
                                          bhalf8 qa0, bhalf8 qa1, int g, int i16,
                                          floatx4 (&ot)[4], float& mC2, float& lp)
{
  const float C2 = 0.125f * 1.44269504f;   // dk^-0.5 * log2(e)
  // ---- S^T = K @ Q^T ----
  floatx4 sa[4] = {};
#pragma unroll
  for (int cb = 0; cb < 4; ++cb) {
    bhalf8 kf0 = *(const bhalf8*)(smem + BUF + cb * 2048 + koff0);
    bhalf8 kf1 = *(const bhalf8*)(smem + BUF + cb * 2048 + koff1);
    sa[cb] = __builtin_amdgcn_mfma_f32_16x16x32_bf16(kf0, qa0, sa[cb], 0, 0, 0);
    sa[cb] = __builtin_amdgcn_mfma_f32_16x16x32_bf16(kf1, qa1, sa[cb], 0, 0, 0);
  }
  // ---- causal mask (wave-uniform: only wave's last tile is partial) ----
  if (t == ntw - 1) {
    const int kv0 = t * 64;
#pragma unroll
    for (int cb = 0; cb < 4; ++cb)
#pragma unroll
      for (int r = 0; r < 4; ++r)
        if (kv0 + cb * 16 + g * 4 + r > qr + i16) sa[cb][r] = -3.0e38f;
  }
  // ---- row max: 15 in-lane + 2 shfl ----
  float pm = sa[0][0];
#pragma unroll
  for (int cb = 0; cb < 4; ++cb)
#pragma unroll
    for (int r = 0; r < 4; ++r)
      pm = fmaxf(pm, sa[cb][r]);
  pm = fmaxf(pm, __shfl_xor(pm, 16));
  pm = fmaxf(pm, __shfl_xor(pm, 32));
  const float pmC2 = pm * C2;
  // ---- defer-max: rescale only when max grows by > 8 (log2 units) ----
  if (!__all(pmC2 - mC2 <= 8.0f)) {
    const float nmax = fmaxf(mC2, pmC2);
    const float al = exp2f(mC2 - nmax);
    mC2 = nmax;
    lp *= al;
#pragma unroll
    for (int da = 0; da < 4; ++da)
#pragma unroll
      for (int r = 0; r < 4; ++r)
        ot[da][r] *= al;
  }
  const float nm = -mC2;
  // ---- P = exp2(S*C2 - mC2); pack via v_cvt_pk_bf16_f32 ----
  u32 pk[8];
  float ps = 0.f;
#pragma unroll
  for (int cb = 0; cb < 4; ++cb) {
    float p0 = exp2f(__builtin_fmaf(sa[cb][0], C2, nm));
    float p1 = exp2f(__builtin_fmaf(sa[cb][1], C2, nm));
    float p2 = exp2f(__builtin_fmaf(sa[cb][2], C2, nm));
    float p3 = exp2f(__builtin_fmaf(sa[cb][3], C2, nm));
    ps += (p0 + p1) + (p2 + p3);
    pk[cb * 2]     = cvtpk(p0, p1);
    pk[cb * 2 + 1] = cvtpk(p2, p3);
  }
  lp += ps;
  // ---- O^T += V^T @ P^T ----
#pragma unroll
  for (int da = 0; da < 4; ++da) {
#pragma unroll
    for (int cb = 0; cb < 4; ++cb) {
      bhalf4 vf = *(const bhalf4*)(smem + BUF + voff[cb] + da * 2048);
      union { u32 u[2]; bhalf4 h; } pu;
      pu.u[0] = pk[cb * 2]; pu.u[1] = pk[cb * 2 + 1];
      ot[da] = __builtin_amdgcn_mfma_f32_16x16x16bf16_1k(vf, pu.h, ot[da], 0, 0, 0);
    }
  }
}

__global__ __launch_bounds__(512, 4) void attn_kernel(const bfu* __restrict__ Q,
                                                      const bfu* __restrict__ Kc,
                                                      const bfu* __restrict__ Vt,
                                                      bfu* __restrict__ Oc)
{
  __shared__ char smem[2 * 16384];
  const int tid = threadIdx.x;
  const int lane = tid & 63;
  const int w = tid >> 6;              // 0..7
  const int g = lane >> 4, i16 = lane & 15;
  const int sw = (i16 & 7) << 4;
  const int bh = blockIdx.x;
  const int y  = blockIdx.y;           // 0..15
  const int spine = 2 * y + 2;         // even
  const int ntw = 2 * y + 1 + (w >> 2);
  const int qr = y * 128 + w * 16;

  const bfu* Qb = Q  + (size_t)bh * S_ * DK_;
  const bfu* Kb = Kc + (size_t)bh * S_ * DK_;
  const bfu* Vb = Vt + (size_t)bh * DK_ * S_;
  const int b = bh >> 4, h = bh & 15;

  // staging: thread covers 16B of K and 16B of V per tile
  const int srow = tid >> 3;           // 0..63
  const int scolb = (tid & 7) * 16;    // byte col in 128B row
  const bfu* kgp = Kb + srow * DK_ + (scolb >> 1);           // += 4096/tile
  const bfu* vgp = Vb + (size_t)srow * S_ + (scolb >> 1);    // += 64/tile
  const int sswz = scolb ^ ((srow & 7) << 4);
  char* kld = smem + srow * 128 + sswz;
  char* vld = smem + 8192 + srow * 128 + sswz;

  // per-wave LDS read offsets (swizzled), buffer base folded as immediate
  const int koff0 = i16 * 128 + ((g * 16) ^ sw);
  const int koff1 = i16 * 128 + (((64 + g * 16)) ^ sw);
  int voff[4];
#pragma unroll
  for (int cb = 0; cb < 4; ++cb)
    voff[cb] = 8192 + i16 * 128 + ((cb * 32 + g * 8) ^ sw);

  // Q B-frags (col=q=i16, k=dk)
  bhalf8 qa0 = *(const bhalf8*)(Qb + (size_t)(qr + i16) * DK_ + g * 8);
  bhalf8 qa1 = *(const bhalf8*)(Qb + (size_t)(qr + i16) * DK_ + 32 + g * 8);

  floatx4 ot[4] = {};          // O^T: col=q=i16, row=dk = da*16 + g*4+r
  float mC2 = -1.0e30f;
  float lp  = 0.f;

  // prologue: tile 0 -> buf0
  bhalf8 kst = *(const bhalf8*)kgp;
  bhalf8 vst = *(const bhalf8*)vgp;
  *(bhalf8*)kld = kst;
  *(bhalf8*)vld = vst;
  __syncthreads();

  const int half = spine >> 1;
  for (int i = 0; ; ++i) {
    const int t0 = 2 * i, t1 = 2 * i + 1;
    const bool more = (i + 1 < half);
    // load tile t1 (consumed after mid-barrier) — overlaps compute(t0)
    kst = *(const bhalf8*)(kgp + (size_t)t1 * 4096);
    vst = *(const bhalf8*)(vgp + t1 * 64);
    if (t0 < ntw)
      attn_tile<0>(smem, t0, ntw, qr, koff0, koff1, voff, qa0, qa1, g, i16, ot, mC2, lp);
    *(bhalf8*)(kld + 16384) = kst;
    *(bhalf8*)(vld + 16384) = vst;
    __syncthreads();
    if (more) {
      kst = *(const bhalf8*)(kgp + (size_t)(t0 + 2) * 4096);
      vst = *(const bhalf8*)(vgp + (t0 + 2) * 64);
    }
    if (t1 < ntw)
      attn_tile<16384>(smem, t1, ntw, qr, koff0, koff1, voff, qa0, qa1, g, i16, ot, mC2, lp);
    if (!more) break;
    *(bhalf8*)kld = kst;
    *(bhalf8*)vld = vst;
    __syncthreads();
  }

  // ---- epilogue: reduce l across g groups, divide, store O^T packed ----
  float lt = lp;
  lt += __shfl_xor(lt, 16);
  lt += __shfl_xor(lt, 32);
  const float rl = 1.0f / lt;
  const size_t rowbase = (size_t)(b * S_ + qr + i16) * D_ + h * 64;
#pragma unroll
  for (int da = 0; da < 4; ++da) {
    union { u32 u[2]; uint2 v; } ov;
    ov.u[0] = cvtpk(ot[da][0] * rl, ot[da][1] * rl);
    ov.u[1] = cvtpk(ot[da][2] * rl, ot[da][3] * rl);
    *(uint2*)(Oc + rowbase + da * 16 + g * 4) = ov.v;
  }
}

// ---------------- output projection GEMM (fp32 out) ----------------
__global__ __launch_bounds__(256) void out_gemm(const bfu* __restrict__ Ab,
                                                const bfu* __restrict__ wob,
                                                float* __restrict__ out)
{
  __shared__ bfu aT[128 * 64], bT[128 * 64];
  floatx4 acc[4][4] = {};
  const int m0 = blockIdx.y * 128, n0 = blockIdx.x * 128;
  gemm_core(Ab, wob, aT, bT, m0, n0, acc);

  const int lane = threadIdx.x & 63;
  const int g = lane >> 4, i16 = lane & 15;
  const int w = threadIdx.x >> 6, wm = w >> 1, wn = w & 1;
#pragma unroll
  for (int fm = 0; fm < 4; ++fm)
#pragma unroll
    for (int fn = 0; fn < 4; ++fn) {
      int col = n0 + wn * 64 + fn * 16 + i16;
#pragma unroll
      for (int r = 0; r < 4; ++r) {
        int mrow = m0 + wm * 64 + fm * 16 + g * 4 + r;
        out[(size_t)mrow * D_ + col] = acc[fm][fn][r];
      }
    }
}

// ---------------- launch ----------------
extern "C" void kernel_launch(void* const* d_in, const int* in_sizes, int n_in,
                              void* d_out, int out_size, void* d_ws, size_t ws_size,
                              hipStream_t stream)
{
  const float* x  = (const float*)d_in[0];
  const float* wq = (const float*)d_in[1];
  const float* wk = (const float*)d_in[2];
  const float* wv = (const float*)d_in[3];
  const float* wo = (const float*)d_in[4];

  bfu* xb  = (bfu*)d_ws;                          // [8192][1024]
  bfu* wqb = xb  + (size_t)M_ * D_;
  bfu* wkb = wqb + (size_t)D_ * D_;
  bfu* wvb = wkb + (size_t)D_ * D_;
  bfu* wob = wvb + (size_t)D_ * D_;
  bfu* Qd  = wob + (size_t)D_ * D_;               // [bh][s][dk]
  bfu* Kd  = Qd  + (size_t)M_ * D_;               // [bh][s][dk]
  bfu* Vtd = Kd  + (size_t)M_ * D_;               // [bh][dk][s]
  bfu* Ad  = Vtd + (size_t)M_ * D_;               // attn out bf16 [b][s][d]

  const int thr = 256;
  cvt_f32_bf16<<<(M_ * D_ / 4 + thr - 1) / thr, thr, 0, stream>>>(x, xb, M_ * D_);
  cvt_f32_bf16<<<(D_ * D_ / 4 + thr - 1) / thr, thr, 0, stream>>>(wq, wqb, D_ * D_);
  cvt_f32_bf16<<<(D_ * D_ / 4 + thr - 1) / thr, thr, 0, stream>>>(wk, wkb, D_ * D_);
  cvt_f32_bf16<<<(D_ * D_ / 4 + thr - 1) / thr, thr, 0, stream>>>(wv, wvb, D_ * D_);
  cvt_f32_bf16<<<(D_ * D_ / 4 + thr - 1) / thr, thr, 0, stream>>>(wo, wob, D_ * D_);

  proj_gemm<<<dim3(8, 64, 3), 256, 0, stream>>>(xb, wqb, wkb, wvb, Qd, Kd, Vtd);
  attn_kernel<<<dim3(B_ * H_, S_ / 128), 512, 0, stream>>>(Qd, Kd, Vtd, Ad);
  out_gemm<<<dim3(8, 64), 256, 0, stream>>>(Ad, wob, (float*)d_out);
}

// Round 8
// 194.759 us; speedup vs baseline: 4.1139x; 1.1292x over previous
//
#include <hip/hip_runtime.h>
#include <stdint.h>

// Problem constants
#define B_ 4
#define S_ 2048
#define D_ 1024
#define H_ 16
#define DK_ 64
#define M_ (B_*S_)   // 8192 rows

typedef __attribute__((ext_vector_type(8))) short bhalf8;   // 8 x bf16 (4 VGPRs)
typedef __attribute__((ext_vector_type(4))) short bhalf4;   // 4 x bf16 (2 VGPRs)
typedef __attribute__((ext_vector_type(4))) float floatx4;  // MFMA accumulator
typedef unsigned short bfu;
typedef unsigned int u32;

// fp32 -> bf16 (RNE), branchless
__device__ __forceinline__ bfu f2bf(float f) {
  union { float f; u32 u; } v; v.f = f;
  u32 r = v.u + 0x7FFFu + ((v.u >> 16) & 1u);
  return (bfu)(r >> 16);
}

// packed fp32x2 -> bf16x2 via HW cvt (RNE); lo16 = a, hi16 = b
__device__ __forceinline__ u32 cvtpk(float a, float b) {
  u32 r;
  asm("v_cvt_pk_bf16_f32 %0, %1, %2" : "=v"(r) : "v"(a), "v"(b));
  return r;
}

// async global->LDS, 16B per lane; LDS dest = wave-uniform base + lane*16
__device__ __forceinline__ void gll16(const bfu* g, bfu* l) {
  __builtin_amdgcn_global_load_lds((__attribute__((address_space(1))) void*)g,
                                   (__attribute__((address_space(3))) void*)l,
                                   16, 0, 0);
}

// ---------------- conversion kernel ----------------
__global__ void cvt_f32_bf16(const float* __restrict__ src, bfu* __restrict__ dst, int n) {
  int i = (blockIdx.x * blockDim.x + threadIdx.x) * 4;
  if (i >= n) return;
  float4 v = *(const float4*)(src + i);
  ushort4 o;
  o.x = f2bf(v.x); o.y = f2bf(v.y); o.z = f2bf(v.z); o.w = f2bf(v.w);
  *(ushort4*)(dst + i) = o;
}

// ---------------- GEMM core (m97-style): C[128x128] = A * B^T, global_load_lds staging ----------------
// 256 thr = 4 waves (2x2). BK=64. LDS linear [128][64] bf16 per operand; DMA dest linear,
// global SOURCE col pre-swizzled by ((l&7)^(l>>3))*16B so reads can use the XOR swizzle
// (rule: swizzle source+read, keep DMA dest linear). 2 barriers per K-step.
__device__ __forceinline__ void gemm_core_gll(const bfu* __restrict__ A,
                                              const bfu* __restrict__ Bw,
                                              bfu* aT, bfu* bT,
                                              int m0, int bn0,
                                              floatx4 (&acc)[4][4])
{
  const int tid  = threadIdx.x;
  const int lane = tid & 63;
  const int g    = lane >> 4;
  const int i16  = lane & 15;
  const int w    = tid >> 6;
  const int wm   = w >> 1, wn = w & 1;

  // staging geometry: instr j of wave w covers rows w*32+j*8 + (lane>>3), 16B each
  const int lrow = lane >> 3;                       // 0..7
  const int scol = ((lane & 7) ^ lrow) << 3;        // pre-swizzled element col (0..56)
  const bfu* As = A  + (size_t)(m0  + w * 32 + lrow) * D_ + scol;
  const bfu* Bs = Bw + (size_t)(bn0 + w * 32 + lrow) * D_ + scol;

  for (int k0 = 0; k0 < D_; k0 += 64) {
#pragma unroll
    for (int j = 0; j < 4; ++j) {
      gll16(As + (size_t)j * 8 * D_ + k0, aT + (w * 4 + j) * 512);
      gll16(Bs + (size_t)j * 8 * D_ + k0, bT + (w * 4 + j) * 512);
    }
    __syncthreads();   // drains vmcnt before barrier (compiler-inserted) -> LDS ready
    const char* aTc = (const char*)aT;
    const char* bTc = (const char*)bT;
#pragma unroll
    for (int kb = 0; kb < 2; ++kb) {
      bhalf8 af[4], bf[4];
#pragma unroll
      for (int f = 0; f < 4; ++f) {
        int arow = wm * 64 + f * 16 + i16;
        af[f] = *(const bhalf8*)(aTc + arow * 128 + ((kb * 64 + g * 16) ^ ((arow & 7) << 4)));
        int brow = wn * 64 + f * 16 + i16;
        bf[f] = *(const bhalf8*)(bTc + brow * 128 + ((kb * 64 + g * 16) ^ ((brow & 7) << 4)));
      }
#pragma unroll
      for (int fm = 0; fm < 4; ++fm)
#pragma unroll
        for (int fn = 0; fn < 4; ++fn)
          acc[fm][fn] = __builtin_amdgcn_mfma_f32_16x16x32_bf16(af[fm], bf[fn], acc[fm][fn], 0, 0, 0);
    }
    __syncthreads();   // protect LDS before next overwrite
  }
}

// ---------------- fused QKV projection GEMM: C[8192 x 3072] ----------------
// grid 1536 blocks 1D. XCD swizzle: c=bid&7 owns y in [c*8,c*8+8) (A 2MB L2-resident),
// sweeping B-tiles xblk-major (each 256KB B-tile fetched ~once per XCD).
__global__ __launch_bounds__(256) void qkv_gemm(const bfu* __restrict__ xb,
                                                const bfu* __restrict__ wqkv,
                                                bfu* __restrict__ Qd,
                                                bfu* __restrict__ Kd,
                                                bfu* __restrict__ Vtd)
{
  __shared__ bfu aT[8192], bT[8192];
  const int bid = blockIdx.x;
  const int wi   = bid >> 3;            // 0..191
  const int xblk = wi >> 3;             // 0..23 (B super-col)
  const int y    = ((bid & 7) << 3) | (wi & 7);   // 0..63 (m-block)
  const int m0   = y * 128;
  const int z    = xblk >> 3;           // 0:Q 1:K 2:V
  const int n0   = (xblk & 7) * 128;    // col within op
  const int bn0  = xblk * 128;          // row in wqkv

  floatx4 acc[4][4] = {};
  gemm_core_gll(xb, wqkv, aT, bT, m0, bn0, acc);

  bfu* dst = (z == 0) ? Qd : (z == 1) ? Kd : Vtd;
  const int lane = threadIdx.x & 63;
  const int g = lane >> 4, i16 = lane & 15;
  const int w = threadIdx.x >> 6, wm = w >> 1, wn = w & 1;
#pragma unroll
  for (int fm = 0; fm < 4; ++fm) {
#pragma unroll
    for (int fn = 0; fn < 4; ++fn) {
      int col = n0 + wn * 64 + fn * 16 + i16;
      int h = col >> 6, dk = col & 63;
#pragma unroll
      for (int r = 0; r < 4; ++r) {
        int mrow = m0 + wm * 64 + fm * 16 + g * 4 + r;
        int b = mrow >> 11, s = mrow & (S_ - 1);
        size_t idx = (z == 2)
            ? ((size_t)((b * H_ + h) * DK_ + dk)) * S_ + s    // V^T
            : ((size_t)((b * H_ + h) * S_ + s)) * DK_ + dk;   // Q,K
        dst[idx] = f2bf(acc[fm][fn][r]);
      }
    }
  }
}

// ---------------- output projection GEMM (fp32 out): C[8192 x 1024] ----------------
__global__ __launch_bounds__(256) void out_gemm(const bfu* __restrict__ Ab,
                                                const bfu* __restrict__ wob,
                                                float* __restrict__ out)
{
  __shared__ bfu aT[8192], bT[8192];
  const int bid = blockIdx.x;
  const int wi   = bid >> 3;            // 0..63
  const int xblk = wi >> 3;             // 0..7
  const int y    = ((bid & 7) << 3) | (wi & 7);
  const int m0   = y * 128;
  const int n0   = xblk * 128;

  floatx4 acc[4][4] = {};
  gemm_core_gll(Ab, wob, aT, bT, m0, n0, acc);

  const int lane = threadIdx.x & 63;
  const int g = lane >> 4, i16 = lane & 15;
  const int w = threadIdx.x >> 6, wm = w >> 1, wn = w & 1;
#pragma unroll
  for (int fm = 0; fm < 4; ++fm)
#pragma unroll
    for (int fn = 0; fn < 4; ++fn) {
      int col = n0 + wn * 64 + fn * 16 + i16;
#pragma unroll
      for (int r = 0; r < 4; ++r) {
        int mrow = m0 + wm * 64 + fm * 16 + g * 4 + r;
        out[(size_t)mrow * D_ + col] = acc[fm][fn][r];
      }
    }
}

// ---------------- flash attention (causal): 8 waves, QBLK=128, shared dbuf LDS K/V ----------------
// (unchanged from round 7 — 133->~60us; S^T = mfma(K,Q) in-register softmax, defer-max,
//  block-cooperative double-buffered LDS staging, q-spine uniform work)
template<int BUF>
__device__ __forceinline__ void attn_tile(const char* smem, int t, int ntw, int qr,
                                          int koff0, int koff1, const int (&voff)[4],
                                          bhalf8 qa0, bhalf8 qa1, int g, int i16,
                                          floatx4 (&ot)[4], float& mC2, float& lp)
{
  const float C2 = 0.125f * 1.44269504f;   // dk^-0.5 * log2(e)
  floatx4 sa[4] = {};
#pragma unroll
  for (int cb = 0; cb < 4; ++cb) {
    bhalf8 kf0 = *(const bhalf8*)(smem + BUF + cb * 2048 + koff0);
    bhalf8 kf1 = *(const bhalf8*)(smem + BUF + cb * 2048 + koff1);
    sa[cb] = __builtin_amdgcn_mfma_f32_16x16x32_bf16(kf0, qa0, sa[cb], 0, 0, 0);
    sa[cb] = __builtin_amdgcn_mfma_f32_16x16x32_bf16(kf1, qa1, sa[cb], 0, 0, 0);
  }
  if (t == ntw - 1) {
    const int kv0 = t * 64;
#pragma unroll
    for (int cb = 0; cb < 4; ++cb)
#pragma unroll
      for (int r = 0; r < 4; ++r)
        if (kv0 + cb * 16 + g * 4 + r > qr + i16) sa[cb][r] = -3.0e38f;
  }
  float pm = sa[0][0];
#pragma unroll
  for (int cb = 0; cb < 4; ++cb)
#pragma unroll
    for (int r = 0; r < 4; ++r)
      pm = fmaxf(pm, sa[cb][r]);
  pm = fmaxf(pm, __shfl_xor(pm, 16));
  pm = fmaxf(pm, __shfl_xor(pm, 32));
  const float pmC2 = pm * C2;
  if (!__all(pmC2 - mC2 <= 8.0f)) {
    const float nmax = fmaxf(mC2, pmC2);
    const float al = exp2f(mC2 - nmax);
    mC2 = nmax;
    lp *= al;
#pragma unroll
    for (int da = 0; da < 4; ++da)
#pragma unroll
      for (int r = 0; r < 4; ++r)
        ot[da][r] *= al;
  }
  const float nm = -mC2;
  u32 pk[8];
  float ps = 0.f;
#pragma unroll
  for (int cb = 0; cb < 4; ++cb) {
    float p0 = exp2f(__builtin_fmaf(sa[cb][0], C2, nm));
    float p1 = exp2f(__builtin_fmaf(sa[cb][1], C2, nm));
    float p2 = exp2f(__builtin_fmaf(sa[cb][2], C2, nm));
    float p3 = exp2f(__builtin_fmaf(sa[cb][3], C2, nm));
    ps += (p0 + p1) + (p2 + p3);
    pk[cb * 2]     = cvtpk(p0, p1);
    pk[cb * 2 + 1] = cvtpk(p2, p3);
  }
  lp += ps;
#pragma unroll
  for (int da = 0; da < 4; ++da) {
#pragma unroll
    for (int cb = 0; cb < 4; ++cb) {
      bhalf4 vf = *(const bhalf4*)(smem + BUF + voff[cb] + da * 2048);
      union { u32 u[2]; bhalf4 h; } pu;
      pu.u[0] = pk[cb * 2]; pu.u[1] = pk[cb * 2 + 1];
      ot[da] = __builtin_amdgcn_mfma_f32_16x16x16bf16_1k(vf, pu.h, ot[da], 0, 0, 0);
    }
  }
}

__global__ __launch_bounds__(512, 4) void attn_kernel(const bfu* __restrict__ Q,
                                                      const bfu* __restrict__ Kc,
                                                      const bfu* __restrict__ Vt,
                                                      bfu* __restrict__ Oc)
{
  __shared__ char smem[2 * 16384];
  const int tid = threadIdx.x;
  const int lane = tid & 63;
  const int w = tid >> 6;              // 0..7
  const int g = lane >> 4, i16 = lane & 15;
  const int sw = (i16 & 7) << 4;
  const int bh = blockIdx.x;
  const int y  = blockIdx.y;           // 0..15
  const int spine = 2 * y + 2;         // even
  const int ntw = 2 * y + 1 + (w >> 2);
  const int qr = y * 128 + w * 16;

  const bfu* Qb = Q  + (size_t)bh * S_ * DK_;
  const bfu* Kb = Kc + (size_t)bh * S_ * DK_;
  const bfu* Vb = Vt + (size_t)bh * DK_ * S_;
  const int b = bh >> 4, h = bh & 15;

  const int srow = tid >> 3;
  const int scolb = (tid & 7) * 16;
  const bfu* kgp = Kb + srow * DK_ + (scolb >> 1);
  const bfu* vgp = Vb + (size_t)srow * S_ + (scolb >> 1);
  const int sswz = scolb ^ ((srow & 7) << 4);
  char* kld = smem + srow * 128 + sswz;
  char* vld = smem + 8192 + srow * 128 + sswz;

  const int koff0 = i16 * 128 + ((g * 16) ^ sw);
  const int koff1 = i16 * 128 + (((64 + g * 16)) ^ sw);
  int voff[4];
#pragma unroll
  for (int cb = 0; cb < 4; ++cb)
    voff[cb] = 8192 + i16 * 128 + ((cb * 32 + g * 8) ^ sw);

  bhalf8 qa0 = *(const bhalf8*)(Qb + (size_t)(qr + i16) * DK_ + g * 8);
  bhalf8 qa1 = *(const bhalf8*)(Qb + (size_t)(qr + i16) * DK_ + 32 + g * 8);

  floatx4 ot[4] = {};
  float mC2 = -1.0e30f;
  float lp  = 0.f;

  bhalf8 kst = *(const bhalf8*)kgp;
  bhalf8 vst = *(const bhalf8*)vgp;
  *(bhalf8*)kld = kst;
  *(bhalf8*)vld = vst;
  __syncthreads();

  const int half = spine >> 1;
  for (int i = 0; ; ++i) {
    const int t0 = 2 * i, t1 = 2 * i + 1;
    const bool more = (i + 1 < half);
    kst = *(const bhalf8*)(kgp + (size_t)t1 * 4096);
    vst = *(const bhalf8*)(vgp + t1 * 64);
    if (t0 < ntw)
      attn_tile<0>(smem, t0, ntw, qr, koff0, koff1, voff, qa0, qa1, g, i16, ot, mC2, lp);
    *(bhalf8*)(kld + 16384) = kst;
    *(bhalf8*)(vld + 16384) = vst;
    __syncthreads();
    if (more) {
      kst = *(const bhalf8*)(kgp + (size_t)(t0 + 2) * 4096);
      vst = *(const bhalf8*)(vgp + (t0 + 2) * 64);
    }
    if (t1 < ntw)
      attn_tile<16384>(smem, t1, ntw, qr, koff0, koff1, voff, qa0, qa1, g, i16, ot, mC2, lp);
    if (!more) break;
    *(bhalf8*)kld = kst;
    *(bhalf8*)vld = vst;
    __syncthreads();
  }

  float lt = lp;
  lt += __shfl_xor(lt, 16);
  lt += __shfl_xor(lt, 32);
  const float rl = 1.0f / lt;
  const size_t rowbase = (size_t)(b * S_ + qr + i16) * D_ + h * 64;
#pragma unroll
  for (int da = 0; da < 4; ++da) {
    union { u32 u[2]; uint2 v; } ov;
    ov.u[0] = cvtpk(ot[da][0] * rl, ot[da][1] * rl);
    ov.u[1] = cvtpk(ot[da][2] * rl, ot[da][3] * rl);
    *(uint2*)(Oc + rowbase + da * 16 + g * 4) = ov.v;
  }
}

// ---------------- launch ----------------
extern "C" void kernel_launch(void* const* d_in, const int* in_sizes, int n_in,
                              void* d_out, int out_size, void* d_ws, size_t ws_size,
                              hipStream_t stream)
{
  const float* x  = (const float*)d_in[0];
  const float* wq = (const float*)d_in[1];
  const float* wk = (const float*)d_in[2];
  const float* wv = (const float*)d_in[3];
  const float* wo = (const float*)d_in[4];

  bfu* xb  = (bfu*)d_ws;                          // [8192][1024]
  bfu* wqb = xb  + (size_t)M_ * D_;               // [3072][1024] = W_qkv contiguous
  bfu* wkb = wqb + (size_t)D_ * D_;
  bfu* wvb = wkb + (size_t)D_ * D_;
  bfu* wob = wvb + (size_t)D_ * D_;
  bfu* Qd  = wob + (size_t)D_ * D_;               // [bh][s][dk]
  bfu* Kd  = Qd  + (size_t)M_ * D_;               // [bh][s][dk]
  bfu* Vtd = Kd  + (size_t)M_ * D_;               // [bh][dk][s]
  bfu* Ad  = Vtd + (size_t)M_ * D_;               // attn out bf16 [b][s][d]

  const int thr = 256;
  cvt_f32_bf16<<<(M_ * D_ / 4 + thr - 1) / thr, thr, 0, stream>>>(x, xb, M_ * D_);
  cvt_f32_bf16<<<(D_ * D_ / 4 + thr - 1) / thr, thr, 0, stream>>>(wq, wqb, D_ * D_);
  cvt_f32_bf16<<<(D_ * D_ / 4 + thr - 1) / thr, thr, 0, stream>>>(wk, wkb, D_ * D_);
  cvt_f32_bf16<<<(D_ * D_ / 4 + thr - 1) / thr, thr, 0, stream>>>(wv, wvb, D_ * D_);
  cvt_f32_bf16<<<(D_ * D_ / 4 + thr - 1) / thr, thr, 0, stream>>>(wo, wob, D_ * D_);

  qkv_gemm<<<1536, 256, 0, stream>>>(xb, wqb, Qd, Kd, Vtd);
  attn_kernel<<<dim3(B_ * H_, S_ / 128), 512, 0, stream>>>(Qd, Kd, Vtd, Ad);
  out_gemm<<<512, 256, 0, stream>>>(Ad, wob, (float*)d_out);
}

// Round 9
// 177.393 us; speedup vs baseline: 4.5166x; 1.0979x over previous
//
#include <hip/hip_runtime.h>
#include <stdint.h>

// Problem constants
#define B_ 4
#define S_ 2048
#define D_ 1024
#define H_ 16
#define DK_ 64
#define M_ (B_*S_)   // 8192 rows

typedef __attribute__((ext_vector_type(8))) short bhalf8;   // 8 x bf16 (4 VGPRs)
typedef __attribute__((ext_vector_type(4))) short bhalf4;   // 4 x bf16 (2 VGPRs)
typedef __attribute__((ext_vector_type(4))) float floatx4;  // MFMA accumulator
typedef unsigned short bfu;
typedef unsigned int u32;

// fp32 -> bf16 (RNE), branchless
__device__ __forceinline__ bfu f2bf(float f) {
  union { float f; u32 u; } v; v.f = f;
  u32 r = v.u + 0x7FFFu + ((v.u >> 16) & 1u);
  return (bfu)(r >> 16);
}

// packed fp32x2 -> bf16x2 via HW cvt (RNE); lo16 = a, hi16 = b
__device__ __forceinline__ u32 cvtpk(float a, float b) {
  u32 r;
  asm("v_cvt_pk_bf16_f32 %0, %1, %2" : "=v"(r) : "v"(a), "v"(b));
  return r;
}

// async global->LDS, 16B per lane; LDS dest = wave-uniform base + lane*16
__device__ __forceinline__ void gll16(const bfu* g, bfu* l) {
  __builtin_amdgcn_global_load_lds((__attribute__((address_space(1))) void*)g,
                                   (__attribute__((address_space(3))) void*)l,
                                   16, 0, 0);
}

// ---------------- fused conversion kernel: x + 4 weights -> contiguous bf16 ws ----------------
__global__ void cvt_all(const float* __restrict__ x,  const float* __restrict__ wq,
                        const float* __restrict__ wk, const float* __restrict__ wv,
                        const float* __restrict__ wo, bfu* __restrict__ dst) {
  const size_t u = ((size_t)blockIdx.x * blockDim.x + threadIdx.x) * 4;
  const size_t XN = (size_t)M_ * D_;           // 8.4M elems, block-aligned boundary
  const float* src;
  if (u < XN) {
    src = x + u;
  } else {
    const size_t v = u - XN;
    const int wsel = (int)(v >> 20);           // D_*D_ = 2^20
    const size_t off = v & ((size_t)(1u << 20) - 1);
    src = ((wsel == 0) ? wq : (wsel == 1) ? wk : (wsel == 2) ? wv : wo) + off;
  }
  float4 vv = *(const float4*)src;
  ushort4 o;
  o.x = f2bf(vv.x); o.y = f2bf(vv.y); o.z = f2bf(vv.z); o.w = f2bf(vv.w);
  *(ushort4*)(dst + u) = o;
}

// ---------------- GEMM core (m97-style): C[128x128] = A * B^T, global_load_lds staging ----------------
__device__ __forceinline__ void gemm_core_gll(const bfu* __restrict__ A,
                                              const bfu* __restrict__ Bw,
                                              bfu* aT, bfu* bT,
                                              int m0, int bn0,
                                              floatx4 (&acc)[4][4])
{
  const int tid  = threadIdx.x;
  const int lane = tid & 63;
  const int g    = lane >> 4;
  const int i16  = lane & 15;
  const int w    = tid >> 6;
  const int wm   = w >> 1, wn = w & 1;

  const int lrow = lane >> 3;                       // 0..7
  const int scol = ((lane & 7) ^ lrow) << 3;        // pre-swizzled element col
  const bfu* As = A  + (size_t)(m0  + w * 32 + lrow) * D_ + scol;
  const bfu* Bs = Bw + (size_t)(bn0 + w * 32 + lrow) * D_ + scol;

  for (int k0 = 0; k0 < D_; k0 += 64) {
#pragma unroll
    for (int j = 0; j < 4; ++j) {
      gll16(As + (size_t)j * 8 * D_ + k0, aT + (w * 4 + j) * 512);
      gll16(Bs + (size_t)j * 8 * D_ + k0, bT + (w * 4 + j) * 512);
    }
    __syncthreads();
    const char* aTc = (const char*)aT;
    const char* bTc = (const char*)bT;
#pragma unroll
    for (int kb = 0; kb < 2; ++kb) {
      bhalf8 af[4], bf[4];
#pragma unroll
      for (int f = 0; f < 4; ++f) {
        int arow = wm * 64 + f * 16 + i16;
        af[f] = *(const bhalf8*)(aTc + arow * 128 + ((kb * 64 + g * 16) ^ ((arow & 7) << 4)));
        int brow = wn * 64 + f * 16 + i16;
        bf[f] = *(const bhalf8*)(bTc + brow * 128 + ((kb * 64 + g * 16) ^ ((brow & 7) << 4)));
      }
#pragma unroll
      for (int fm = 0; fm < 4; ++fm)
#pragma unroll
        for (int fn = 0; fn < 4; ++fn)
          acc[fm][fn] = __builtin_amdgcn_mfma_f32_16x16x32_bf16(af[fm], bf[fn], acc[fm][fn], 0, 0, 0);
    }
    __syncthreads();
  }
}

// ---------------- fused QKV projection GEMM: C[8192 x 3072] ----------------
__global__ __launch_bounds__(256) void qkv_gemm(const bfu* __restrict__ xb,
                                                const bfu* __restrict__ wqkv,
                                                bfu* __restrict__ Qd,
                                                bfu* __restrict__ Kd,
                                                bfu* __restrict__ Vtd)
{
  __shared__ bfu aT[8192], bT[8192];
  const int bid = blockIdx.x;
  const int wi   = bid >> 3;
  const int xblk = wi >> 3;                       // 0..23
  const int y    = ((bid & 7) << 3) | (wi & 7);   // 0..63
  const int m0   = y * 128;
  const int z    = xblk >> 3;                     // 0:Q 1:K 2:V
  const int n0   = (xblk & 7) * 128;
  const int bn0  = xblk * 128;

  floatx4 acc[4][4] = {};
  gemm_core_gll(xb, wqkv, aT, bT, m0, bn0, acc);

  bfu* dst = (z == 0) ? Qd : (z == 1) ? Kd : Vtd;
  const int lane = threadIdx.x & 63;
  const int g = lane >> 4, i16 = lane & 15;
  const int w = threadIdx.x >> 6, wm = w >> 1, wn = w & 1;
#pragma unroll
  for (int fm = 0; fm < 4; ++fm) {
#pragma unroll
    for (int fn = 0; fn < 4; ++fn) {
      int col = n0 + wn * 64 + fn * 16 + i16;
      int h = col >> 6, dk = col & 63;
#pragma unroll
      for (int r = 0; r < 4; ++r) {
        int mrow = m0 + wm * 64 + fm * 16 + g * 4 + r;
        int b = mrow >> 11, s = mrow & (S_ - 1);
        size_t idx = (z == 2)
            ? ((size_t)((b * H_ + h) * DK_ + dk)) * S_ + s    // V^T
            : ((size_t)((b * H_ + h) * S_ + s)) * DK_ + dk;   // Q,K
        dst[idx] = f2bf(acc[fm][fn][r]);
      }
    }
  }
}

// ---------------- output projection GEMM (fp32 out): C[8192 x 1024] ----------------
__global__ __launch_bounds__(256) void out_gemm(const bfu* __restrict__ Ab,
                                                const bfu* __restrict__ wob,
                                                float* __restrict__ out)
{
  __shared__ bfu aT[8192], bT[8192];
  const int bid = blockIdx.x;
  const int wi   = bid >> 3;
  const int xblk = wi >> 3;                       // 0..7
  const int y    = ((bid & 7) << 3) | (wi & 7);
  const int m0   = y * 128;
  const int n0   = xblk * 128;

  floatx4 acc[4][4] = {};
  gemm_core_gll(Ab, wob, aT, bT, m0, n0, acc);

  const int lane = threadIdx.x & 63;
  const int g = lane >> 4, i16 = lane & 15;
  const int w = threadIdx.x >> 6, wm = w >> 1, wn = w & 1;
#pragma unroll
  for (int fm = 0; fm < 4; ++fm)
#pragma unroll
    for (int fn = 0; fn < 4; ++fn) {
      int col = n0 + wn * 64 + fn * 16 + i16;
#pragma unroll
      for (int r = 0; r < 4; ++r) {
        int mrow = m0 + wm * 64 + fm * 16 + g * 4 + r;
        out[(size_t)mrow * D_ + col] = acc[fm][fn][r];
      }
    }
}

// ---------------- flash attention (causal): 8 waves, QBLK=128, paired q-blocks ----------------
// grid (B*H, 8): block runs q-blocks {y0, 15-y0} -> uniform 34 staged kv-tiles (no tail).
// V LDS swizzle includes bit3 of row (i16&8) so ds_read_b64 lanes i16/i16+8 hit distinct banks;
// V staged as two bhalf4 halves at matching swizzled addresses.
template<int BUF>
__device__ __forceinline__ void attn_tile(const char* smem, int t, int ntw, int qr,
                                          int koff0, int koff1, const int (&voff)[4],
                                          bhalf8 qa0, bhalf8 qa1, int g, int i16,
                                          floatx4 (&ot)[4], float& mC2, float& lp)
{
  const float C2 = 0.125f * 1.44269504f;   // dk^-0.5 * log2(e)
  floatx4 sa[4] = {};
#pragma unroll
  for (int cb = 0; cb < 4; ++cb) {
    bhalf8 kf0 = *(const bhalf8*)(smem + BUF + cb * 2048 + koff0);
    bhalf8 kf1 = *(const bhalf8*)(smem + BUF + cb * 2048 + koff1);
    sa[cb] = __builtin_amdgcn_mfma_f32_16x16x32_bf16(kf0, qa0, sa[cb], 0, 0, 0);
    sa[cb] = __builtin_amdgcn_mfma_f32_16x16x32_bf16(kf1, qa1, sa[cb], 0, 0, 0);
  }
  if (t == ntw - 1) {
    const int kv0 = t * 64;
#pragma unroll
    for (int cb = 0; cb < 4; ++cb)
#pragma unroll
      for (int r = 0; r < 4; ++r)
        if (kv0 + cb * 16 + g * 4 + r > qr + i16) sa[cb][r] = -3.0e38f;
  }
  float pm = sa[0][0];
#pragma unroll
  for (int cb = 0; cb < 4; ++cb)
#pragma unroll
    for (int r = 0; r < 4; ++r)
      pm = fmaxf(pm, sa[cb][r]);
  pm = fmaxf(pm, __shfl_xor(pm, 16));
  pm = fmaxf(pm, __shfl_xor(pm, 32));
  const float pmC2 = pm * C2;
  if (!__all(pmC2 - mC2 <= 8.0f)) {
    const float nmax = fmaxf(mC2, pmC2);
    const float al = exp2f(mC2 - nmax);
    mC2 = nmax;
    lp *= al;
#pragma unroll
    for (int da = 0; da < 4; ++da)
#pragma unroll
      for (int r = 0; r < 4; ++r)
        ot[da][r] *= al;
  }
  const float nm = -mC2;
  u32 pk[8];
  float ps = 0.f;
#pragma unroll
  for (int cb = 0; cb < 4; ++cb) {
    float p0 = exp2f(__builtin_fmaf(sa[cb][0], C2, nm));
    float p1 = exp2f(__builtin_fmaf(sa[cb][1], C2, nm));
    float p2 = exp2f(__builtin_fmaf(sa[cb][2], C2, nm));
    float p3 = exp2f(__builtin_fmaf(sa[cb][3], C2, nm));
    ps += (p0 + p1) + (p2 + p3);
    pk[cb * 2]     = cvtpk(p0, p1);
    pk[cb * 2 + 1] = cvtpk(p2, p3);
  }
  lp += ps;
#pragma unroll
  for (int da = 0; da < 4; ++da) {
#pragma unroll
    for (int cb = 0; cb < 4; ++cb) {
      bhalf4 vf = *(const bhalf4*)(smem + BUF + voff[cb] + da * 2048);
      union { u32 u[2]; bhalf4 h; } pu;
      pu.u[0] = pk[cb * 2]; pu.u[1] = pk[cb * 2 + 1];
      ot[da] = __builtin_amdgcn_mfma_f32_16x16x16bf16_1k(vf, pu.h, ot[da], 0, 0, 0);
    }
  }
}

__global__ __launch_bounds__(512, 4) void attn_kernel(const bfu* __restrict__ Q,
                                                      const bfu* __restrict__ Kc,
                                                      const bfu* __restrict__ Vt,
                                                      bfu* __restrict__ Oc)
{
  __shared__ char smem[2 * 16384];
  const int tid = threadIdx.x;
  const int lane = tid & 63;
  const int w = tid >> 6;              // 0..7
  const int g = lane >> 4, i16 = lane & 15;
  const int sw = (i16 & 7) << 4;
  const int bh = blockIdx.x;
  const int y0 = blockIdx.y;           // 0..7

  const bfu* Qb = Q  + (size_t)bh * S_ * DK_;
  const bfu* Kb = Kc + (size_t)bh * S_ * DK_;
  const bfu* Vb = Vt + (size_t)bh * DK_ * S_;
  const int b = bh >> 4, h = bh & 15;

  // staging: thread covers 16B of K and 16B of V per tile
  const int srow = tid >> 3;           // 0..63
  const int scolb = (tid & 7) * 16;
  const bfu* kgp = Kb + srow * DK_ + (scolb >> 1);
  const bfu* vgp = Vb + (size_t)srow * S_ + (scolb >> 1);
  char* kld = smem + srow * 128 + (scolb ^ ((srow & 7) << 4));
  const int vsw = ((srow & 7) << 4) | (srow & 8);
  char* vld0 = smem + 8192 + srow * 128 + ((scolb    ) ^ vsw);
  char* vld1 = smem + 8192 + srow * 128 + ((scolb + 8) ^ vsw);

  // per-wave LDS read offsets (swizzled)
  const int koff0 = i16 * 128 + ((g * 16) ^ sw);
  const int koff1 = i16 * 128 + ((64 + g * 16) ^ sw);
  const int vswr = sw | (i16 & 8);
  int voff[4];
#pragma unroll
  for (int cb = 0; cb < 4; ++cb)
    voff[cb] = 8192 + i16 * 128 + ((cb * 32 + g * 8) ^ vswr);

  for (int pass = 0; pass < 2; ++pass) {
    const int y = pass ? (15 - y0) : y0;
    const int ntw = 2 * y + 1 + (w >> 2);
    const int qr = y * 128 + w * 16;
    const int spine = 2 * y + 2;       // even

    bhalf8 qa0 = *(const bhalf8*)(Qb + (size_t)(qr + i16) * DK_ + g * 8);
    bhalf8 qa1 = *(const bhalf8*)(Qb + (size_t)(qr + i16) * DK_ + 32 + g * 8);

    floatx4 ot[4] = {};
    float mC2 = -1.0e30f;
    float lp  = 0.f;

    union { bhalf8 h8; bhalf4 h4[2]; } vu;
    bhalf8 kst = *(const bhalf8*)kgp;
    bhalf8 vst = *(const bhalf8*)vgp;
    *(bhalf8*)kld = kst;
    vu.h8 = vst;
    *(bhalf4*)vld0 = vu.h4[0]; *(bhalf4*)vld1 = vu.h4[1];
    __syncthreads();

    const int half = spine >> 1;
    for (int i = 0; ; ++i) {
      const int t0 = 2 * i, t1 = 2 * i + 1;
      const bool more = (i + 1 < half);
      kst = *(const bhalf8*)(kgp + (size_t)t1 * 4096);
      vst = *(const bhalf8*)(vgp + t1 * 64);
      if (t0 < ntw)
        attn_tile<0>(smem, t0, ntw, qr, koff0, koff1, voff, qa0, qa1, g, i16, ot, mC2, lp);
      *(bhalf8*)(kld + 16384) = kst;
      vu.h8 = vst;
      *(bhalf4*)(vld0 + 16384) = vu.h4[0]; *(bhalf4*)(vld1 + 16384) = vu.h4[1];
      __syncthreads();
      if (more) {
        kst = *(const bhalf8*)(kgp + (size_t)(t0 + 2) * 4096);
        vst = *(const bhalf8*)(vgp + (t0 + 2) * 64);
      }
      if (t1 < ntw)
        attn_tile<16384>(smem, t1, ntw, qr, koff0, koff1, voff, qa0, qa1, g, i16, ot, mC2, lp);
      if (!more) break;
      *(bhalf8*)kld = kst;
      vu.h8 = vst;
      *(bhalf4*)vld0 = vu.h4[0]; *(bhalf4*)vld1 = vu.h4[1];
      __syncthreads();
    }
    __syncthreads();   // all waves done with buffers before next pass reuses them

    float lt = lp;
    lt += __shfl_xor(lt, 16);
    lt += __shfl_xor(lt, 32);
    const float rl = 1.0f / lt;
    const size_t rowbase = (size_t)(b * S_ + qr + i16) * D_ + h * 64;
#pragma unroll
    for (int da = 0; da < 4; ++da) {
      union { u32 u[2]; uint2 v; } ov;
      ov.u[0] = cvtpk(ot[da][0] * rl, ot[da][1] * rl);
      ov.u[1] = cvtpk(ot[da][2] * rl, ot[da][3] * rl);
      *(uint2*)(Oc + rowbase + da * 16 + g * 4) = ov.v;
    }
  }
}

// ---------------- launch ----------------
extern "C" void kernel_launch(void* const* d_in, const int* in_sizes, int n_in,
                              void* d_out, int out_size, void* d_ws, size_t ws_size,
                              hipStream_t stream)
{
  const float* x  = (const float*)d_in[0];
  const float* wq = (const float*)d_in[1];
  const float* wk = (const float*)d_in[2];
  const float* wv = (const float*)d_in[3];
  const float* wo = (const float*)d_in[4];

  bfu* xb  = (bfu*)d_ws;                          // [8192][1024]
  bfu* wqb = xb  + (size_t)M_ * D_;               // [3072][1024] = W_qkv contiguous
  bfu* wob = wqb + (size_t)3 * D_ * D_;           // [1024][1024]
  bfu* Qd  = wob + (size_t)D_ * D_;               // [bh][s][dk]
  bfu* Kd  = Qd  + (size_t)M_ * D_;               // [bh][s][dk]
  bfu* Vtd = Kd  + (size_t)M_ * D_;               // [bh][dk][s]
  bfu* Ad  = Vtd + (size_t)M_ * D_;               // attn out bf16 [b][s][d]

  const size_t total = (size_t)M_ * D_ + 4 * (size_t)D_ * D_;   // 12582912
  cvt_all<<<(int)(total / 4 / 256), 256, 0, stream>>>(x, wq, wk, wv, wo, xb);

  qkv_gemm<<<1536, 256, 0, stream>>>(xb, wqb, Qd, Kd, Vtd);
  attn_kernel<<<dim3(B_ * H_, 8), 512, 0, stream>>>(Qd, Kd, Vtd, Ad);
  out_gemm<<<512, 256, 0, stream>>>(Ad, wob, (float*)d_out);
}